// Round 1
// 475.729 us; speedup vs baseline: 1.1246x; 1.1246x over previous
//
#include <hip/hip_runtime.h>

// MSDeformAttn encoder layer — bf16 MFMA GEMMs (global_load_lds staging) +
// wave-per-query deformable sampling with fused softmax (no barriers).
#define DMODEL 256
#define NHEAD 8
#define NPOINT 4
#define NLEVEL 4
#define DHEAD 32
#define MLPD 1024
#define BSZ 2
#define LQTOK 21760
#define NTOK (BSZ * LQTOK)  // 43520
#define LNEPS 1e-6f
#define FFN_CHUNK 21760     // NTOK/2, divisible by 128

typedef __attribute__((ext_vector_type(8))) short short8;
typedef __attribute__((ext_vector_type(4))) float f32x4;

__device__ __forceinline__ float bf2f(unsigned short u) {
  unsigned int i = ((unsigned int)u) << 16;
  return __builtin_bit_cast(float, i);
}
__device__ __forceinline__ unsigned short f2bf(float f) {
  unsigned int i = __builtin_bit_cast(unsigned int, f);
  i += 0x7fff + ((i >> 16) & 1);  // round-to-nearest-even
  return (unsigned short)(i >> 16);
}
__device__ __forceinline__ float bflo(unsigned int u) {
  return __builtin_bit_cast(float, u << 16);
}
__device__ __forceinline__ float bfhi(unsigned int u) {
  return __builtin_bit_cast(float, u & 0xffff0000u);
}

// async global->LDS, 16B per lane; lds dest = wave-uniform base + lane*16
__device__ __forceinline__ void gload_lds16(const unsigned short* g,
                                            unsigned short* lds) {
  __builtin_amdgcn_global_load_lds(
      (const __attribute__((address_space(1))) unsigned int*)g,
      (__attribute__((address_space(3))) unsigned int*)lds, 16, 0, 0);
}

// ---------------- layernorm: wave-per-row, no LDS/barriers -----------------
// o = bf16(LN(in)*g + beta); if EMITQ also q = bf16(bf2f(o) + pos)
// (bit-identical to the old ADDPOS staging numerics).
template <bool EMITQ>
__global__ __launch_bounds__(256) void ln_bf16(
    const float* __restrict__ in, const float* __restrict__ g,
    const float* __restrict__ beta, unsigned short* __restrict__ o,
    const float* __restrict__ pos, unsigned short* __restrict__ q) {
  const int w = threadIdx.x >> 6, lane = threadIdx.x & 63;
  const size_t t = (size_t)blockIdx.x * 4 + w;
  const size_t base = t * DMODEL + lane * 4;
  float4 v = *(const float4*)(in + base);
  float s = (v.x + v.y) + (v.z + v.w);
#pragma unroll
  for (int off = 32; off; off >>= 1) s += __shfl_xor(s, off, 64);
  float mu = s * (1.0f / DMODEL);
  float dx = v.x - mu, dy = v.y - mu, dz = v.z - mu, dw = v.w - mu;
  float s2 = (dx * dx + dy * dy) + (dz * dz + dw * dw);
#pragma unroll
  for (int off = 32; off; off >>= 1) s2 += __shfl_xor(s2, off, 64);
  float rs = rsqrtf(s2 * (1.0f / DMODEL) + LNEPS);
  float4 gg = *(const float4*)(g + lane * 4);
  float4 bb = *(const float4*)(beta + lane * 4);
  unsigned short r0 = f2bf(dx * rs * gg.x + bb.x);
  unsigned short r1 = f2bf(dy * rs * gg.y + bb.y);
  unsigned short r2 = f2bf(dz * rs * gg.z + bb.z);
  unsigned short r3 = f2bf(dw * rs * gg.w + bb.w);
  unsigned int lo = ((unsigned int)r1 << 16) | r0;
  unsigned int hi = ((unsigned int)r3 << 16) | r2;
  *(uint2*)(o + base) = make_uint2(lo, hi);
  if (EMITQ) {
    float4 p = *(const float4*)(pos + base);
    unsigned short q0 = f2bf(bf2f(r0) + p.x);
    unsigned short q1 = f2bf(bf2f(r1) + p.y);
    unsigned short q2 = f2bf(bf2f(r2) + p.z);
    unsigned short q3 = f2bf(bf2f(r3) + p.w);
    unsigned int ql = ((unsigned int)q1 << 16) | q0;
    unsigned int qh = ((unsigned int)q3 << 16) | q2;
    *(uint2*)(q + base) = make_uint2(ql, qh);
  }
}

// ---------------- transpose + cast: Wt[n][k] = bf16(W[k][n]) ----------------
__global__ __launch_bounds__(256) void transpose_bf16(const float* __restrict__ W,
                                                      unsigned short* __restrict__ Wt,
                                                      int K, int N) {
  __shared__ float tile[32][33];
  int k0 = blockIdx.x * 32, n0 = blockIdx.y * 32;
  int tx = threadIdx.x & 31, ty = threadIdx.x >> 5;  // 32 x 8
  for (int i = ty; i < 32; i += 8) tile[i][tx] = W[(size_t)(k0 + i) * N + n0 + tx];
  __syncthreads();
  for (int i = ty; i < 32; i += 8)
    Wt[(size_t)(n0 + i) * K + k0 + tx] = f2bf(tile[tx][i]);
}

// ---------------- bf16 MFMA GEMM: C = A @ Wt^T + bias [...] ----------------
// Tile 128x128, BK=32, 256 threads = 4 waves (2x2 of 64x64), 4x4 MFMA
// 16x16x32 per wave. A: bf16 [M][K]. Wt: bf16 [N][K]. Unpadded pitch-32 LDS
// (m97 layout — required by global_load_lds). OMODE: 1=bf16, 2=bf16+relu,
// 3=f32+res.
template <int OMODE>
__global__ __launch_bounds__(256) void gemm_mfma(
    const unsigned short* __restrict__ A, const unsigned short* __restrict__ Wt,
    const float* __restrict__ bias, const float* __restrict__ res,
    void* __restrict__ Cout, int M, int N, int K) {
  __shared__ __attribute__((aligned(16))) unsigned short As[128 * 32];
  __shared__ __attribute__((aligned(16))) unsigned short Bs[128 * 32];
  const int tid = threadIdx.x;
  const int m0 = blockIdx.x * 128, n0 = blockIdx.y * 128;
  const int wave = tid >> 6, lane = tid & 63;
  const int wm = (wave & 1) * 64, wn = (wave >> 1) * 64;
  const int lr = lane & 15, quad = lane >> 4;
  f32x4 acc[4][4] = {};
  for (int k0 = 0; k0 < K; k0 += 32) {
    __syncthreads();
#pragma unroll
    for (int r = 0; r < 2; r++) {
      int c = r * 256 + tid;
      int row = c >> 2, col8 = (c & 3) * 8;
      gload_lds16(Wt + (size_t)(n0 + row) * K + k0 + col8,
                  &Bs[(r * 256 + wave * 64) * 8]);
    }
#pragma unroll
    for (int r = 0; r < 2; r++) {
      int c = r * 256 + tid;
      int row = c >> 2, col8 = (c & 3) * 8;
      gload_lds16(A + (size_t)(m0 + row) * K + k0 + col8,
                  &As[(r * 256 + wave * 64) * 8]);
    }
    __syncthreads();
    short8 af[4], bfr[4];
#pragma unroll
    for (int i = 0; i < 4; i++)
      af[i] = *(const short8*)(&As[(wm + i * 16 + lr) * 32 + quad * 8]);
#pragma unroll
    for (int j = 0; j < 4; j++)
      bfr[j] = *(const short8*)(&Bs[(wn + j * 16 + lr) * 32 + quad * 8]);
#pragma unroll
    for (int i = 0; i < 4; i++)
#pragma unroll
      for (int j = 0; j < 4; j++)
        acc[i][j] = __builtin_amdgcn_mfma_f32_16x16x32_bf16(af[i], bfr[j],
                                                            acc[i][j], 0, 0, 0);
  }
  // epilogue: C/D layout col=lane&15, row=quad*4+reg
#pragma unroll
  for (int i = 0; i < 4; i++) {
    int rbase = m0 + wm + i * 16 + quad * 4;
#pragma unroll
    for (int j = 0; j < 4; j++) {
      int col = n0 + wn + j * 16 + lr;
      float bv = bias[col];
#pragma unroll
      for (int r = 0; r < 4; r++) {
        size_t idx = (size_t)(rbase + r) * N + col;
        float v = acc[i][j][r] + bv;
        if (OMODE == 2) v = fmaxf(v, 0.0f);
        if (OMODE == 3) v += res[idx];
        if (OMODE == 3)
          ((float*)Cout)[idx] = v;
        else
          ((unsigned short*)Cout)[idx] = f2bf(v);
      }
    }
  }
}

// ---------------- deformable sampling + fused softmax ----------------
// Wave-per-query: 4 queries/block, NO __syncthreads (wave-synchronous LDS).
// Phase 1: lane handles units u=2*lane, 2*lane+1 (same (h,level) pair).
//   softmax over each head's 16 logits lives in 8 lanes (2/lane): 3-level
//   shfl_xor butterflies. Clamped flat indices + prescaled masked bilinear
//   weights -> LDS laid out [pt][h][4] so phase-2 reads are conflict-free.
// Phase 2: lane = (h, g): g = 4-channel group; lane accumulates ALL 16
//   points for its channels (no cross-lane combine), all 64 lanes store.
__global__ __launch_bounds__(256) void deform_sample(
    const unsigned short* __restrict__ val, const unsigned short* __restrict__ off,
    const unsigned short* __restrict__ logits, const float* __restrict__ refp,
    unsigned short* __restrict__ out) {
  __shared__ __attribute__((aligned(16))) int sIdx[4][16][8][4];
  __shared__ __attribute__((aligned(16))) float sW[4][16][8][4];
  const int w = threadIdx.x >> 6, lane = threadIdx.x & 63;
  const int bq = blockIdx.x * 4 + w;
  const int b = bq / LQTOK;
  {
    const int HW_[4] = {128, 64, 32, 16};
    const int LSI_[4] = {0, 16384, 20480, 21504};
    int u0 = 2 * lane;
    int h = u0 >> 4;
    int lvl = (u0 >> 2) & 3;
    int pt0 = u0 & 15;
    int HW = HW_[lvl];
    float2 rp = ((const float2*)refp)[(size_t)bq * 4 + lvl];
    uint2 ov = *(const uint2*)(off + (size_t)bq * 256 + 4 * lane);
    unsigned int lgu = *(const unsigned int*)(logits + (size_t)bq * 128 + 2 * lane);
    float lg0 = bflo(lgu), lg1 = bfhi(lgu);
    // fused softmax over this head's 16 logits (8 lanes x 2)
    float mx = fmaxf(lg0, lg1);
#pragma unroll
    for (int s = 1; s < 8; s <<= 1) mx = fmaxf(mx, __shfl_xor(mx, s, 64));
    float e0 = expf(lg0 - mx), e1 = expf(lg1 - mx);
    float es = e0 + e1;
#pragma unroll
    for (int s = 1; s < 8; s <<= 1) es += __shfl_xor(es, s, 64);
    float inv = 1.0f / es;
    float a01[2] = {e0 * inv, e1 * inv};
    unsigned int ovv[2] = {ov.x, ov.y};
    int hb = h * DHEAD;
#pragma unroll
    for (int c = 0; c < 2; c++) {
      float x = fmaf(rp.x, (float)HW, bflo(ovv[c])) - 0.5f;
      float y = fmaf(rp.y, (float)HW, bfhi(ovv[c])) - 0.5f;
      float xf = floorf(x), yf = floorf(y);
      int x0 = (int)xf, y0 = (int)yf;
      float lx = x - xf, ly = y - yf;
      int x0c = min(max(x0, 0), HW - 1);
      int x1c = min(max(x0 + 1, 0), HW - 1);
      int y0c = min(max(y0, 0), HW - 1);
      int y1c = min(max(y0 + 1, 0), HW - 1);
      float m0x = (x0 >= 0 && x0 < HW) ? 1.f : 0.f;
      float m1x = (x0 + 1 >= 0 && x0 + 1 < HW) ? 1.f : 0.f;
      float m0y = (y0 >= 0 && y0 < HW) ? 1.f : 0.f;
      float m1y = (y0 + 1 >= 0 && y0 + 1 < HW) ? 1.f : 0.f;
      float a = a01[c];
      int* ip = sIdx[w][pt0 + c][h];
      float* wp = sW[w][pt0 + c][h];
      ip[0] = (LSI_[lvl] + y0c * HW + x0c) * DMODEL + hb;
      ip[1] = (LSI_[lvl] + y0c * HW + x1c) * DMODEL + hb;
      ip[2] = (LSI_[lvl] + y1c * HW + x0c) * DMODEL + hb;
      ip[3] = (LSI_[lvl] + y1c * HW + x1c) * DMODEL + hb;
      wp[0] = (1.f - lx) * (1.f - ly) * m0x * m0y * a;
      wp[1] = lx * (1.f - ly) * m1x * m0y * a;
      wp[2] = (1.f - lx) * ly * m0x * m1y * a;
      wp[3] = lx * ly * m1x * m1y * a;
    }
  }
  // wave-synchronous handoff: same wave wrote, same wave reads (in-order DS
  // pipe); wave_barrier pins compiler ordering at zero HW cost.
  __builtin_amdgcn_wave_barrier();
  const int h2 = lane >> 3, g = lane & 7;
  const unsigned short* vb = val + (size_t)b * LQTOK * DMODEL + g * 4;
  float a0 = 0.f, a1 = 0.f, a2 = 0.f, a3 = 0.f;
#pragma unroll
  for (int pb = 0; pb < 4; pb++) {
    int4 ix[4];
    float4 wt[4];
#pragma unroll
    for (int p = 0; p < 4; p++) {
      ix[p] = *(const int4*)sIdx[w][pb * 4 + p][h2];
      wt[p] = *(const float4*)sW[w][pb * 4 + p][h2];
    }
    uint2 v4[4][4];
#pragma unroll
    for (int p = 0; p < 4; p++) {
      v4[p][0] = *(const uint2*)(vb + ix[p].x);
      v4[p][1] = *(const uint2*)(vb + ix[p].y);
      v4[p][2] = *(const uint2*)(vb + ix[p].z);
      v4[p][3] = *(const uint2*)(vb + ix[p].w);
    }
#pragma unroll
    for (int p = 0; p < 4; p++) {
      float wk[4] = {wt[p].x, wt[p].y, wt[p].z, wt[p].w};
#pragma unroll
      for (int k = 0; k < 4; k++) {
        uint2 u = v4[p][k];
        a0 = fmaf(wk[k], bflo(u.x), a0);
        a1 = fmaf(wk[k], bfhi(u.x), a1);
        a2 = fmaf(wk[k], bflo(u.y), a2);
        a3 = fmaf(wk[k], bfhi(u.y), a3);
      }
    }
  }
  unsigned int o0 = ((unsigned int)f2bf(a1) << 16) | f2bf(a0);
  unsigned int o1 = ((unsigned int)f2bf(a3) << 16) | f2bf(a2);
  *(uint2*)(out + (size_t)bq * 256 + h2 * 32 + g * 4) = make_uint2(o0, o1);
}

// ---------------- launch ----------------
extern "C" void kernel_launch(void* const* d_in, const int* in_sizes, int n_in,
                              void* d_out, int out_size, void* d_ws,
                              size_t ws_size, hipStream_t stream) {
  const float* src    = (const float*)d_in[0];
  const float* pos    = (const float*)d_in[1];
  const float* refp   = (const float*)d_in[2];
  const float* g1     = (const float*)d_in[5];
  const float* beta1  = (const float*)d_in[6];
  const float* w_off  = (const float*)d_in[7];
  const float* b_off  = (const float*)d_in[8];
  const float* w_attn = (const float*)d_in[9];
  const float* b_attn = (const float*)d_in[10];
  const float* w_val  = (const float*)d_in[11];
  const float* b_val  = (const float*)d_in[12];
  const float* w_out  = (const float*)d_in[13];
  const float* b_out  = (const float*)d_in[14];
  const float* g2     = (const float*)d_in[15];
  const float* beta2  = (const float*)d_in[16];
  const float* w_fc1  = (const float*)d_in[17];
  const float* b_fc1  = (const float*)d_in[18];
  const float* w_fc2  = (const float*)d_in[19];
  const float* b_fc2  = (const float*)d_in[20];
  float* out = (float*)d_out;

  // Workspace: 135.2 MB total (layout unchanged from the verified baseline).
  const size_t NT = (size_t)NTOK;
  unsigned short* b1 = (unsigned short*)d_ws;  // x bf16 -> sampled -> ffn hid
  unsigned short* b2 = b1 + NT * 256;          // val bf16        -> ffn hid
  unsigned short* b3 = b2 + NT * 256;          // off bf16 -> y bf16
  float* b4 = (float*)(b3 + NT * 256);         // q bf16 (exact-fit reuse)
  float* b5 = b4 + NT * 128;                   // logits bf16 -> src2 f32
  unsigned short* wvalT  = (unsigned short*)(b5 + NT * 256);  // [256][256]
  unsigned short* woffT  = wvalT + 256 * 256;                 // [256][256]
  unsigned short* wattnT = woffT + 256 * 256;                 // [128][256]
  unsigned short* woutT  = wattnT + 128 * 256;                // [256][256]
  unsigned short* wfc1T  = woutT + 256 * 256;                 // [1024][256]
  unsigned short* wfc2T  = wfc1T + 1024 * 256;                // [256][1024]

  unsigned short* qb  = (unsigned short*)b4;   // q = x+pos, bf16 [NT][256]
  unsigned short* lgb = (unsigned short*)b5;   // logits bf16 [NT][128]
                                               // (b5 free until step 6)

  // 0. weight transposes (f32 -> bf16, [K][N] -> [N][K])
  transpose_bf16<<<dim3(8, 8), 256, 0, stream>>>(w_val, wvalT, 256, 256);
  transpose_bf16<<<dim3(8, 8), 256, 0, stream>>>(w_off, woffT, 256, 256);
  transpose_bf16<<<dim3(8, 4), 256, 0, stream>>>(w_attn, wattnT, 256, 128);
  transpose_bf16<<<dim3(8, 8), 256, 0, stream>>>(w_out, woutT, 256, 256);
  transpose_bf16<<<dim3(8, 32), 256, 0, stream>>>(w_fc1, wfc1T, 256, 1024);
  transpose_bf16<<<dim3(32, 8), 256, 0, stream>>>(w_fc2, wfc2T, 1024, 256);

  const int MT = NTOK / 128;  // 340

  // 1. x = LN(src) -> b1 (bf16); q = bf16(x)+pos -> qb (bf16)
  ln_bf16<true><<<NTOK / 4, 256, 0, stream>>>(src, g1, beta1, b1, pos, qb);
  // 2. val = x @ w_val + b_val -> bf16
  gemm_mfma<1><<<dim3(MT, 2), 256, 0, stream>>>(b1, wvalT, b_val, nullptr, b2,
                                                NTOK, 256, 256);
  // 3. off = q @ w_off + b_off -> bf16 (fast gload_lds path now)
  gemm_mfma<1><<<dim3(MT, 2), 256, 0, stream>>>(qb, woffT, b_off, nullptr, b3,
                                                NTOK, 256, 256);
  // 4. logits = q @ w_attn + b_attn -> bf16 (softmax fused into sampler)
  gemm_mfma<1><<<dim3(MT, 1), 256, 0, stream>>>(qb, wattnT, b_attn, nullptr,
                                                lgb, NTOK, 128, 256);
  // 5. sampling (with fused softmax) -> b1 (x dead, q dead after step 4)
  deform_sample<<<NTOK / 4, 256, 0, stream>>>(b2, b3, lgb, refp, b1);
  // 6. src2 = sampled @ w_out + b_out + src -> f32 (overwrites logits region)
  gemm_mfma<3><<<dim3(MT, 2), 256, 0, stream>>>(b1, woutT, b_out, src, b5,
                                                NTOK, 256, 256);
  // 7. y = LN(src2) -> bf16 (off dead)
  ln_bf16<false><<<NTOK / 4, 256, 0, stream>>>(b5, g2, beta2, b3, nullptr,
                                               nullptr);
  // 8/9. FFN in 2 chunks; hidden (21760x1024 bf16) exactly fills b1+b2.
  unsigned short* hid = b1;
  for (int c = 0; c < 2; c++) {
    size_t ro = (size_t)c * FFN_CHUNK;
    gemm_mfma<2><<<dim3(FFN_CHUNK / 128, 8), 256, 0, stream>>>(
        b3 + ro * 256, wfc1T, b_fc1, nullptr, hid, FFN_CHUNK, 1024, 256);
    gemm_mfma<3><<<dim3(FFN_CHUNK / 128, 2), 256, 0, stream>>>(
        hid, wfc2T, b_fc2, b5 + ro * 256, out + ro * 256, FFN_CHUNK, 256, 1024);
  }
}

// Round 3
// 445.764 us; speedup vs baseline: 1.2003x; 1.0672x over previous
//
#include <hip/hip_runtime.h>

// MSDeformAttn encoder layer — bf16 MFMA GEMMs (global_load_lds staging) +
// wave-per-query deformable sampling with fused softmax (no barriers).
#define DMODEL 256
#define NHEAD 8
#define NPOINT 4
#define NLEVEL 4
#define DHEAD 32
#define MLPD 1024
#define BSZ 2
#define LQTOK 21760
#define NTOK (BSZ * LQTOK)  // 43520
#define LNEPS 1e-6f

typedef __attribute__((ext_vector_type(8))) short short8;
typedef __attribute__((ext_vector_type(4))) float f32x4;
typedef __attribute__((ext_vector_type(2))) float f32x2;

__device__ __forceinline__ float bf2f(unsigned short u) {
  unsigned int i = ((unsigned int)u) << 16;
  return __builtin_bit_cast(float, i);
}
__device__ __forceinline__ unsigned short f2bf(float f) {
  unsigned int i = __builtin_bit_cast(unsigned int, f);
  i += 0x7fff + ((i >> 16) & 1);  // round-to-nearest-even
  return (unsigned short)(i >> 16);
}
__device__ __forceinline__ float bflo(unsigned int u) {
  return __builtin_bit_cast(float, u << 16);
}
__device__ __forceinline__ float bfhi(unsigned int u) {
  return __builtin_bit_cast(float, u & 0xffff0000u);
}

// d = a * {b,b} + d  (packed f32 FMA; all VOP3P operands must be VGPR pairs,
// so the scalar weight is duplicated into a pair first)
__device__ __forceinline__ void pk_fma_bcast(f32x2& d, f32x2 a, float b) {
  f32x2 bb;
  bb[0] = b;
  bb[1] = b;
  asm("v_pk_fma_f32 %0, %1, %2, %0" : "+v"(d) : "v"(a), "v"(bb));
}

// async global->LDS, 16B per lane; lds dest = wave-uniform base + lane*16
__device__ __forceinline__ void gload_lds16(const unsigned short* g,
                                            unsigned short* lds) {
  __builtin_amdgcn_global_load_lds(
      (const __attribute__((address_space(1))) unsigned int*)g,
      (__attribute__((address_space(3))) unsigned int*)lds, 16, 0, 0);
}

// ---------------- layernorm: wave-per-row, no LDS/barriers -----------------
// o = bf16(LN(in)*g + beta); if EMITQ also q = bf16(bf2f(o) + pos)
template <bool EMITQ>
__global__ __launch_bounds__(256) void ln_bf16(
    const float* __restrict__ in, const float* __restrict__ g,
    const float* __restrict__ beta, unsigned short* __restrict__ o,
    const float* __restrict__ pos, unsigned short* __restrict__ q) {
  const int w = threadIdx.x >> 6, lane = threadIdx.x & 63;
  const size_t t = (size_t)blockIdx.x * 4 + w;
  const size_t base = t * DMODEL + lane * 4;
  float4 v = *(const float4*)(in + base);
  float s = (v.x + v.y) + (v.z + v.w);
#pragma unroll
  for (int off = 32; off; off >>= 1) s += __shfl_xor(s, off, 64);
  float mu = s * (1.0f / DMODEL);
  float dx = v.x - mu, dy = v.y - mu, dz = v.z - mu, dw = v.w - mu;
  float s2 = (dx * dx + dy * dy) + (dz * dz + dw * dw);
#pragma unroll
  for (int off = 32; off; off >>= 1) s2 += __shfl_xor(s2, off, 64);
  float rs = rsqrtf(s2 * (1.0f / DMODEL) + LNEPS);
  float4 gg = *(const float4*)(g + lane * 4);
  float4 bb = *(const float4*)(beta + lane * 4);
  unsigned short r0 = f2bf(dx * rs * gg.x + bb.x);
  unsigned short r1 = f2bf(dy * rs * gg.y + bb.y);
  unsigned short r2 = f2bf(dz * rs * gg.z + bb.z);
  unsigned short r3 = f2bf(dw * rs * gg.w + bb.w);
  unsigned int lo = ((unsigned int)r1 << 16) | r0;
  unsigned int hi = ((unsigned int)r3 << 16) | r2;
  *(uint2*)(o + base) = make_uint2(lo, hi);
  if (EMITQ) {
    float4 p = *(const float4*)(pos + base);
    unsigned short q0 = f2bf(bf2f(r0) + p.x);
    unsigned short q1 = f2bf(bf2f(r1) + p.y);
    unsigned short q2 = f2bf(bf2f(r2) + p.z);
    unsigned short q3 = f2bf(bf2f(r3) + p.w);
    unsigned int ql = ((unsigned int)q1 << 16) | q0;
    unsigned int qh = ((unsigned int)q3 << 16) | q2;
    *(uint2*)(q + base) = make_uint2(ql, qh);
  }
}

// ---------------- transpose + cast: Wt[n][k] = bf16(W[k][n]) ----------------
__global__ __launch_bounds__(256) void transpose_bf16(const float* __restrict__ W,
                                                      unsigned short* __restrict__ Wt,
                                                      int K, int N) {
  __shared__ float tile[32][33];
  int k0 = blockIdx.x * 32, n0 = blockIdx.y * 32;
  int tx = threadIdx.x & 31, ty = threadIdx.x >> 5;  // 32 x 8
  for (int i = ty; i < 32; i += 8) tile[i][tx] = W[(size_t)(k0 + i) * N + n0 + tx];
  __syncthreads();
  for (int i = ty; i < 32; i += 8)
    Wt[(size_t)(n0 + i) * K + k0 + tx] = f2bf(tile[tx][i]);
}

// ---------------- bf16 MFMA GEMM: C = A @ Wt^T + bias [...] ----------------
// Tile 128x128, BK=32, 256 threads = 4 waves (2x2 of 64x64), 4x4 MFMA
// 16x16x32 per wave. A: bf16 [M][K]. Wt: bf16 [N][K]. Unpadded pitch-32 LDS
// (m97 layout — required by global_load_lds).
// OMODE: 1=bf16, 2=bf16+relu, 3=f32+res, 4=bf16 split (cols<256 -> Cout
// stride 256, cols>=256 -> Cout2 stride 128, bias2 in `res`).
template <int OMODE>
__global__ __launch_bounds__(256) void gemm_mfma(
    const unsigned short* __restrict__ A, const unsigned short* __restrict__ Wt,
    const float* __restrict__ bias, const float* __restrict__ res,
    void* __restrict__ Cout, void* __restrict__ Cout2, int M, int N, int K) {
  __shared__ __attribute__((aligned(16))) unsigned short As[128 * 32];
  __shared__ __attribute__((aligned(16))) unsigned short Bs[128 * 32];
  const int tid = threadIdx.x;
  const int m0 = blockIdx.x * 128, n0 = blockIdx.y * 128;
  const int wave = tid >> 6, lane = tid & 63;
  const int wm = (wave & 1) * 64, wn = (wave >> 1) * 64;
  const int lr = lane & 15, quad = lane >> 4;
  f32x4 acc[4][4] = {};
  for (int k0 = 0; k0 < K; k0 += 32) {
    __syncthreads();
#pragma unroll
    for (int r = 0; r < 2; r++) {
      int c = r * 256 + tid;
      int row = c >> 2, col8 = (c & 3) * 8;
      gload_lds16(Wt + (size_t)(n0 + row) * K + k0 + col8,
                  &Bs[(r * 256 + wave * 64) * 8]);
    }
#pragma unroll
    for (int r = 0; r < 2; r++) {
      int c = r * 256 + tid;
      int row = c >> 2, col8 = (c & 3) * 8;
      gload_lds16(A + (size_t)(m0 + row) * K + k0 + col8,
                  &As[(r * 256 + wave * 64) * 8]);
    }
    __syncthreads();
    short8 af[4], bfr[4];
#pragma unroll
    for (int i = 0; i < 4; i++)
      af[i] = *(const short8*)(&As[(wm + i * 16 + lr) * 32 + quad * 8]);
#pragma unroll
    for (int j = 0; j < 4; j++)
      bfr[j] = *(const short8*)(&Bs[(wn + j * 16 + lr) * 32 + quad * 8]);
#pragma unroll
    for (int i = 0; i < 4; i++)
#pragma unroll
      for (int j = 0; j < 4; j++)
        acc[i][j] = __builtin_amdgcn_mfma_f32_16x16x32_bf16(af[i], bfr[j],
                                                            acc[i][j], 0, 0, 0);
  }
  // epilogue: C/D layout col=lane&15, row=quad*4+reg
#pragma unroll
  for (int i = 0; i < 4; i++) {
    int rbase = m0 + wm + i * 16 + quad * 4;
#pragma unroll
    for (int j = 0; j < 4; j++) {
      int col = n0 + wn + j * 16 + lr;
      float bv = (OMODE == 4 && col >= 256) ? res[col - 256] : bias[col];
#pragma unroll
      for (int r = 0; r < 4; r++) {
        float v = acc[i][j][r] + bv;
        if (OMODE == 2) v = fmaxf(v, 0.0f);
        if (OMODE == 4) {
          size_t row = (size_t)(rbase + r);
          if (col < 256)
            ((unsigned short*)Cout)[row * 256 + col] = f2bf(v);
          else
            ((unsigned short*)Cout2)[row * 128 + (col - 256)] = f2bf(v);
        } else {
          size_t idx = (size_t)(rbase + r) * N + col;
          if (OMODE == 3) {
            ((float*)Cout)[idx] = v + res[idx];
          } else {
            ((unsigned short*)Cout)[idx] = f2bf(v);
          }
        }
      }
    }
  }
}

// ---------------- deformable sampling + fused softmax ----------------
// Wave-per-query: 4 queries/block, NO __syncthreads (wave-synchronous LDS).
// Phase 1: lane handles units u=2*lane, 2*lane+1 (same (h,level) pair).
//   softmax over each head's 16 logits lives in 8 lanes (2/lane): 3-level
//   shfl_xor butterflies. Byte-scaled clamped flat indices + prescaled
//   masked bilinear weights -> LDS as [pt][h ^ (pt&7)][4] (XOR swizzle +
//   explicit int4/float4 stores -> conflict-free b128 writes).
// Phase 2: lane = (h, g): g = 4-channel group; lane accumulates ALL 16
//   points for its channels via packed-f32 FMA; all 64 lanes store.
__global__ __launch_bounds__(256) void deform_sample(
    const unsigned short* __restrict__ val, const unsigned short* __restrict__ off,
    const unsigned short* __restrict__ logits, const float* __restrict__ refp,
    unsigned short* __restrict__ out) {
  __shared__ __attribute__((aligned(16))) int sIdx[4][16][8][4];
  __shared__ __attribute__((aligned(16))) float sW[4][16][8][4];
  const int w = threadIdx.x >> 6, lane = threadIdx.x & 63;
  const int bq = blockIdx.x * 4 + w;
  const int b = __builtin_amdgcn_readfirstlane(bq / LQTOK);
  {
    const int HW_[4] = {128, 64, 32, 16};
    const int LSI_[4] = {0, 16384, 20480, 21504};
    int u0 = 2 * lane;
    int h = u0 >> 4;
    int lvl = (u0 >> 2) & 3;
    int pt0 = u0 & 15;
    int HW = HW_[lvl];
    float2 rp = ((const float2*)refp)[(size_t)bq * 4 + lvl];
    uint2 ov = *(const uint2*)(off + (size_t)bq * 256 + 4 * lane);
    unsigned int lgu = *(const unsigned int*)(logits + (size_t)bq * 128 + 2 * lane);
    float lg0 = bflo(lgu), lg1 = bfhi(lgu);
    // fused softmax over this head's 16 logits (8 lanes x 2)
    float mx = fmaxf(lg0, lg1);
#pragma unroll
    for (int s = 1; s < 8; s <<= 1) mx = fmaxf(mx, __shfl_xor(mx, s, 64));
    float e0 = expf(lg0 - mx), e1 = expf(lg1 - mx);
    float es = e0 + e1;
#pragma unroll
    for (int s = 1; s < 8; s <<= 1) es += __shfl_xor(es, s, 64);
    float inv = 1.0f / es;
    float a01[2] = {e0 * inv, e1 * inv};
    unsigned int ovv[2] = {ov.x, ov.y};
    int hb2 = h * (DHEAD * 2);  // head byte offset
#pragma unroll
    for (int c = 0; c < 2; c++) {
      float x = fmaf(rp.x, (float)HW, bflo(ovv[c])) - 0.5f;
      float y = fmaf(rp.y, (float)HW, bfhi(ovv[c])) - 0.5f;
      float xf = floorf(x), yf = floorf(y);
      int x0 = (int)xf, y0 = (int)yf;
      float lx = x - xf, ly = y - yf;
      int x0c = min(max(x0, 0), HW - 1);
      int x1c = min(max(x0 + 1, 0), HW - 1);
      int y0c = min(max(y0, 0), HW - 1);
      int y1c = min(max(y0 + 1, 0), HW - 1);
      float m0x = (x0 >= 0 && x0 < HW) ? 1.f : 0.f;
      float m1x = (x0 + 1 >= 0 && x0 + 1 < HW) ? 1.f : 0.f;
      float m0y = (y0 >= 0 && y0 < HW) ? 1.f : 0.f;
      float m1y = (y0 + 1 >= 0 && y0 + 1 < HW) ? 1.f : 0.f;
      float a = a01[c];
      int pt = pt0 + c;
      int hs = h ^ (pt & 7);
      int r0 = (LSI_[lvl] + y0c * HW) * (DMODEL * 2) + hb2;
      int r1 = (LSI_[lvl] + y1c * HW) * (DMODEL * 2) + hb2;
      *(int4*)sIdx[w][pt][hs] =
          make_int4(r0 + x0c * (DMODEL * 2), r0 + x1c * (DMODEL * 2),
                    r1 + x0c * (DMODEL * 2), r1 + x1c * (DMODEL * 2));
      *(float4*)sW[w][pt][hs] =
          make_float4((1.f - lx) * (1.f - ly) * m0x * m0y * a,
                      lx * (1.f - ly) * m1x * m0y * a,
                      (1.f - lx) * ly * m0x * m1y * a,
                      lx * ly * m1x * m1y * a);
    }
  }
  // wave-synchronous handoff: same wave wrote, same wave reads.
  __builtin_amdgcn_wave_barrier();
  const int h2 = lane >> 3, g = lane & 7;
  const char* basep =
      (const char*)val + (size_t)b * ((size_t)LQTOK * DMODEL * 2);
  const int goff = g * 8;  // byte offset of this lane's 4-channel group
  f32x2 a01v = {0.f, 0.f}, a23v = {0.f, 0.f};
#pragma unroll
  for (int pb = 0; pb < 4; pb++) {
    int4 ix[4];
    float4 wt4[4];
#pragma unroll
    for (int p = 0; p < 4; p++) {
      int pt = pb * 4 + p;
      int hs = h2 ^ (pt & 7);
      ix[p] = *(const int4*)sIdx[w][pt][hs];
      wt4[p] = *(const float4*)sW[w][pt][hs];
    }
    uint2 v4[4][4];
#pragma unroll
    for (int p = 0; p < 4; p++) {
      v4[p][0] = *(const uint2*)(basep + (unsigned)(ix[p].x + goff));
      v4[p][1] = *(const uint2*)(basep + (unsigned)(ix[p].y + goff));
      v4[p][2] = *(const uint2*)(basep + (unsigned)(ix[p].z + goff));
      v4[p][3] = *(const uint2*)(basep + (unsigned)(ix[p].w + goff));
    }
#pragma unroll
    for (int p = 0; p < 4; p++) {
      float wk[4] = {wt4[p].x, wt4[p].y, wt4[p].z, wt4[p].w};
#pragma unroll
      for (int k = 0; k < 4; k++) {
        uint2 u = v4[p][k];
        f32x2 vlo, vhi;
        vlo[0] = bflo(u.x);
        vlo[1] = bfhi(u.x);
        vhi[0] = bflo(u.y);
        vhi[1] = bfhi(u.y);
        pk_fma_bcast(a01v, vlo, wk[k]);
        pk_fma_bcast(a23v, vhi, wk[k]);
      }
    }
  }
  unsigned int o0 = ((unsigned int)f2bf(a01v[1]) << 16) | f2bf(a01v[0]);
  unsigned int o1 = ((unsigned int)f2bf(a23v[1]) << 16) | f2bf(a23v[0]);
  *(uint2*)(out + (size_t)bq * 256 + h2 * 32 + g * 4) = make_uint2(o0, o1);
}

// ---------------- launch ----------------
extern "C" void kernel_launch(void* const* d_in, const int* in_sizes, int n_in,
                              void* d_out, int out_size, void* d_ws,
                              size_t ws_size, hipStream_t stream) {
  const float* src    = (const float*)d_in[0];
  const float* pos    = (const float*)d_in[1];
  const float* refp   = (const float*)d_in[2];
  const float* g1     = (const float*)d_in[5];
  const float* beta1  = (const float*)d_in[6];
  const float* w_off  = (const float*)d_in[7];
  const float* b_off  = (const float*)d_in[8];
  const float* w_attn = (const float*)d_in[9];
  const float* b_attn = (const float*)d_in[10];
  const float* w_val  = (const float*)d_in[11];
  const float* b_val  = (const float*)d_in[12];
  const float* w_out  = (const float*)d_in[13];
  const float* b_out  = (const float*)d_in[14];
  const float* g2     = (const float*)d_in[15];
  const float* beta2  = (const float*)d_in[16];
  const float* w_fc1  = (const float*)d_in[17];
  const float* b_fc1  = (const float*)d_in[18];
  const float* w_fc2  = (const float*)d_in[19];
  const float* b_fc2  = (const float*)d_in[20];
  float* out = (float*)d_out;

  // Workspace layout (byte budget identical to the verified baseline):
  //  b1..b4 (4 x 22.28MB, contiguous) double as the full FFN hidden (89.1MB)
  //  b5 (44.6MB) holds logits bf16 then y bf16; src2 goes straight to d_out.
  const size_t NT = (size_t)NTOK;
  unsigned short* b1 = (unsigned short*)d_ws;  // x bf16 -> sampled -> hid
  unsigned short* b2 = b1 + NT * 256;          // val bf16          -> hid
  unsigned short* b3 = b2 + NT * 256;          // off bf16          -> hid
  unsigned short* b4 = b3 + NT * 256;          // q bf16            -> hid
  unsigned short* b5 = b4 + NT * 256;          // logits bf16 -> y bf16
  unsigned short* wvalT  = b5 + NT * 512;      // [256][256]
  unsigned short* woffaT = wvalT + 256 * 256;  // [384][256] (off|attn merged)
  unsigned short* woutT  = woffaT + 384 * 256; // [256][256]
  unsigned short* wfc1T  = woutT + 256 * 256;  // [1024][256]
  unsigned short* wfc2T  = wfc1T + 1024 * 256; // [256][1024]

  unsigned short* qb  = b4;  // q = x+pos, bf16 [NT][256]
  unsigned short* lgb = b5;  // logits bf16 [NT][128]
  unsigned short* yb  = b5;  // y bf16 [NT][256] (after logits dead)
  unsigned short* hid = b1;  // FFN hidden bf16 [NT][1024] spans b1..b4

  // 0. weight transposes (f32 -> bf16, [K][N] -> [N][K])
  transpose_bf16<<<dim3(8, 8), 256, 0, stream>>>(w_val, wvalT, 256, 256);
  transpose_bf16<<<dim3(8, 8), 256, 0, stream>>>(w_off, woffaT, 256, 256);
  transpose_bf16<<<dim3(8, 4), 256, 0, stream>>>(w_attn, woffaT + 256 * 256,
                                                 256, 128);
  transpose_bf16<<<dim3(8, 8), 256, 0, stream>>>(w_out, woutT, 256, 256);
  transpose_bf16<<<dim3(8, 32), 256, 0, stream>>>(w_fc1, wfc1T, 256, 1024);
  transpose_bf16<<<dim3(32, 8), 256, 0, stream>>>(w_fc2, wfc2T, 1024, 256);

  const int MT = NTOK / 128;  // 340

  // 1. x = LN(src) -> b1 (bf16); q = bf16(x)+pos -> qb (bf16)
  ln_bf16<true><<<NTOK / 4, 256, 0, stream>>>(src, g1, beta1, b1, pos, qb);
  // 2. val = x @ w_val + b_val -> b2 (bf16)
  gemm_mfma<1><<<dim3(MT, 2), 256, 0, stream>>>(b1, wvalT, b_val, nullptr, b2,
                                                nullptr, NTOK, 256, 256);
  // 3. [off | logits] = q @ [w_off | w_attn] (one pass over q, N=384)
  gemm_mfma<4><<<dim3(MT, 3), 256, 0, stream>>>(qb, woffaT, b_off, b_attn, b3,
                                                lgb, NTOK, 384, 256);
  // 4. sampling (fused softmax) -> b1 (x dead, q dead)
  deform_sample<<<NTOK / 4, 256, 0, stream>>>(b2, b3, lgb, refp, b1);
  // 5. src2 = sampled @ w_out + b_out + src -> d_out (f32)
  gemm_mfma<3><<<dim3(MT, 2), 256, 0, stream>>>(b1, woutT, b_out, src, out,
                                                nullptr, NTOK, 256, 256);
  // 6. y = LN(src2) -> yb (bf16; overwrites dead logits)
  ln_bf16<false><<<NTOK / 4, 256, 0, stream>>>(out, g2, beta2, yb, nullptr,
                                               nullptr);
  // 7. hid = relu(y @ w_fc1 + b_fc1) -> b1..b4 (89.1MB, all dead)
  gemm_mfma<2><<<dim3(MT, 8), 256, 0, stream>>>(yb, wfc1T, b_fc1, nullptr, hid,
                                                nullptr, NTOK, 1024, 256);
  // 8. out = hid @ w_fc2 + b_fc2 + src2(d_out) -> d_out (read-then-write)
  gemm_mfma<3><<<dim3(MT, 2), 256, 0, stream>>>(hid, wfc2T, b_fc2, out, out,
                                                nullptr, NTOK, 256, 1024);
}

// Round 4
// 437.820 us; speedup vs baseline: 1.2220x; 1.0181x over previous
//
#include <hip/hip_runtime.h>

// MSDeformAttn encoder layer — bf16 MFMA GEMMs (global_load_lds staging,
// XCD-chunked block swizzle) + wave-per-query deformable sampling with
// fused softmax (no barriers, op_sel packed-FMA).
#define DMODEL 256
#define NHEAD 8
#define NPOINT 4
#define NLEVEL 4
#define DHEAD 32
#define MLPD 1024
#define BSZ 2
#define LQTOK 21760
#define NTOK (BSZ * LQTOK)  // 43520
#define LNEPS 1e-6f

typedef __attribute__((ext_vector_type(8))) short short8;
typedef __attribute__((ext_vector_type(4))) float f32x4;
typedef __attribute__((ext_vector_type(2))) float f32x2;

__device__ __forceinline__ float bf2f(unsigned short u) {
  unsigned int i = ((unsigned int)u) << 16;
  return __builtin_bit_cast(float, i);
}
__device__ __forceinline__ unsigned short f2bf(float f) {
  unsigned int i = __builtin_bit_cast(unsigned int, f);
  i += 0x7fff + ((i >> 16) & 1);  // round-to-nearest-even
  return (unsigned short)(i >> 16);
}
__device__ __forceinline__ float bflo(unsigned int u) {
  return __builtin_bit_cast(float, u << 16);
}
__device__ __forceinline__ float bfhi(unsigned int u) {
  return __builtin_bit_cast(float, u & 0xffff0000u);
}

// d += a * b.lo (both halves use word0 of b)   [VOP3P: all srcs are pairs]
__device__ __forceinline__ void pk_fma_blo(f32x2& d, f32x2 a, f32x2 b) {
  asm("v_pk_fma_f32 %0, %1, %2, %0 op_sel:[0,0,0] op_sel_hi:[1,0,1]"
      : "+v"(d)
      : "v"(a), "v"(b));
}
// d += a * b.hi (both halves use word1 of b)
__device__ __forceinline__ void pk_fma_bhi(f32x2& d, f32x2 a, f32x2 b) {
  asm("v_pk_fma_f32 %0, %1, %2, %0 op_sel:[0,1,0] op_sel_hi:[1,1,1]"
      : "+v"(d)
      : "v"(a), "v"(b));
}

// async global->LDS, 16B per lane; lds dest = wave-uniform base + lane*16
__device__ __forceinline__ void gload_lds16(const unsigned short* g,
                                            unsigned short* lds) {
  __builtin_amdgcn_global_load_lds(
      (const __attribute__((address_space(1))) unsigned int*)g,
      (__attribute__((address_space(3))) unsigned int*)lds, 16, 0, 0);
}

// ---------------- layernorm: wave-per-row, no LDS/barriers -----------------
// o = bf16(LN(in)*g + beta); if EMITQ also q = bf16(bf2f(o) + pos)
template <bool EMITQ>
__global__ __launch_bounds__(256) void ln_bf16(
    const float* __restrict__ in, const float* __restrict__ g,
    const float* __restrict__ beta, unsigned short* __restrict__ o,
    const float* __restrict__ pos, unsigned short* __restrict__ q) {
  const int w = threadIdx.x >> 6, lane = threadIdx.x & 63;
  const size_t t = (size_t)blockIdx.x * 4 + w;
  const size_t base = t * DMODEL + lane * 4;
  float4 v = *(const float4*)(in + base);
  float s = (v.x + v.y) + (v.z + v.w);
#pragma unroll
  for (int off = 32; off; off >>= 1) s += __shfl_xor(s, off, 64);
  float mu = s * (1.0f / DMODEL);
  float dx = v.x - mu, dy = v.y - mu, dz = v.z - mu, dw = v.w - mu;
  float s2 = (dx * dx + dy * dy) + (dz * dz + dw * dw);
#pragma unroll
  for (int off = 32; off; off >>= 1) s2 += __shfl_xor(s2, off, 64);
  float rs = rsqrtf(s2 * (1.0f / DMODEL) + LNEPS);
  float4 gg = *(const float4*)(g + lane * 4);
  float4 bb = *(const float4*)(beta + lane * 4);
  unsigned short r0 = f2bf(dx * rs * gg.x + bb.x);
  unsigned short r1 = f2bf(dy * rs * gg.y + bb.y);
  unsigned short r2 = f2bf(dz * rs * gg.z + bb.z);
  unsigned short r3 = f2bf(dw * rs * gg.w + bb.w);
  unsigned int lo = ((unsigned int)r1 << 16) | r0;
  unsigned int hi = ((unsigned int)r3 << 16) | r2;
  *(uint2*)(o + base) = make_uint2(lo, hi);
  if (EMITQ) {
    float4 p = *(const float4*)(pos + base);
    unsigned short q0 = f2bf(bf2f(r0) + p.x);
    unsigned short q1 = f2bf(bf2f(r1) + p.y);
    unsigned short q2 = f2bf(bf2f(r2) + p.z);
    unsigned short q3 = f2bf(bf2f(r3) + p.w);
    unsigned int ql = ((unsigned int)q1 << 16) | q0;
    unsigned int qh = ((unsigned int)q3 << 16) | q2;
    *(uint2*)(q + base) = make_uint2(ql, qh);
  }
}

// ---------------- transpose + cast: Wt[n][k] = bf16(W[k][n]) ----------------
__global__ __launch_bounds__(256) void transpose_bf16(const float* __restrict__ W,
                                                      unsigned short* __restrict__ Wt,
                                                      int K, int N) {
  __shared__ float tile[32][33];
  int k0 = blockIdx.x * 32, n0 = blockIdx.y * 32;
  int tx = threadIdx.x & 31, ty = threadIdx.x >> 5;  // 32 x 8
  for (int i = ty; i < 32; i += 8) tile[i][tx] = W[(size_t)(k0 + i) * N + n0 + tx];
  __syncthreads();
  for (int i = ty; i < 32; i += 8)
    Wt[(size_t)(n0 + i) * K + k0 + tx] = f2bf(tile[tx][i]);
}

// ---------------- bf16 MFMA GEMM: C = A @ Wt^T + bias [...] ----------------
// Tile 128x128, BK=32, 256 threads = 4 waves (2x2 of 64x64), 4x4 MFMA
// 16x16x32 per wave. A: bf16 [M][K]. Wt: bf16 [N][K]. Unpadded pitch-32 LDS
// (m97 layout — required by global_load_lds).
// Block swizzle: bijective XCD-chunked remap (m204), column-tile-fastest
// within a chunk so same-row-tile blocks run adjacently on one XCD and the
// A-panel stays hot in that XCD's L2 (A refetch ~N/128 x -> ~1x).
// OMODE: 1=bf16, 2=bf16+relu, 3=f32+res, 4=bf16 split (cols<256 -> Cout
// stride 256, cols>=256 -> Cout2 stride 128, bias2 in `res`).
template <int OMODE>
__global__ __launch_bounds__(256) void gemm_mfma(
    const unsigned short* __restrict__ A, const unsigned short* __restrict__ Wt,
    const float* __restrict__ bias, const float* __restrict__ res,
    void* __restrict__ Cout, void* __restrict__ Cout2, int M, int N, int K) {
  __shared__ __attribute__((aligned(16))) unsigned short As[128 * 32];
  __shared__ __attribute__((aligned(16))) unsigned short Bs[128 * 32];
  const int tid = threadIdx.x;
  // ---- XCD-chunked bijective swizzle ----
  const unsigned gx = gridDim.x, gy = gridDim.y;
  const unsigned nwg = gx * gy;
  const unsigned orig = blockIdx.y * gx + blockIdx.x;
  const unsigned xcd = orig & 7u, rest = orig >> 3;
  const unsigned qq = nwg >> 3, rr = nwg & 7u;
  const unsigned wgid =
      (xcd < rr ? xcd * (qq + 1) : rr * (qq + 1) + (xcd - rr) * qq) + rest;
  const int m0 = (int)(wgid / gy) * 128;  // consecutive wgid share m0
  const int n0 = (int)(wgid % gy) * 128;
  const int wave = tid >> 6, lane = tid & 63;
  const int wm = (wave & 1) * 64, wn = (wave >> 1) * 64;
  const int lr = lane & 15, quad = lane >> 4;
  f32x4 acc[4][4] = {};
  for (int k0 = 0; k0 < K; k0 += 32) {
    __syncthreads();
#pragma unroll
    for (int r = 0; r < 2; r++) {
      int c = r * 256 + tid;
      int row = c >> 2, col8 = (c & 3) * 8;
      gload_lds16(Wt + (size_t)(n0 + row) * K + k0 + col8,
                  &Bs[(r * 256 + wave * 64) * 8]);
    }
#pragma unroll
    for (int r = 0; r < 2; r++) {
      int c = r * 256 + tid;
      int row = c >> 2, col8 = (c & 3) * 8;
      gload_lds16(A + (size_t)(m0 + row) * K + k0 + col8,
                  &As[(r * 256 + wave * 64) * 8]);
    }
    __syncthreads();
    short8 af[4], bfr[4];
#pragma unroll
    for (int i = 0; i < 4; i++)
      af[i] = *(const short8*)(&As[(wm + i * 16 + lr) * 32 + quad * 8]);
#pragma unroll
    for (int j = 0; j < 4; j++)
      bfr[j] = *(const short8*)(&Bs[(wn + j * 16 + lr) * 32 + quad * 8]);
#pragma unroll
    for (int i = 0; i < 4; i++)
#pragma unroll
      for (int j = 0; j < 4; j++)
        acc[i][j] = __builtin_amdgcn_mfma_f32_16x16x32_bf16(af[i], bfr[j],
                                                            acc[i][j], 0, 0, 0);
  }
  // epilogue: C/D layout col=lane&15, row=quad*4+reg
#pragma unroll
  for (int i = 0; i < 4; i++) {
    int rbase = m0 + wm + i * 16 + quad * 4;
#pragma unroll
    for (int j = 0; j < 4; j++) {
      int col = n0 + wn + j * 16 + lr;
      float bv = (OMODE == 4 && col >= 256) ? res[col - 256] : bias[col];
#pragma unroll
      for (int r = 0; r < 4; r++) {
        float v = acc[i][j][r] + bv;
        if (OMODE == 2) v = fmaxf(v, 0.0f);
        if (OMODE == 4) {
          size_t row = (size_t)(rbase + r);
          if (col < 256)
            ((unsigned short*)Cout)[row * 256 + col] = f2bf(v);
          else
            ((unsigned short*)Cout2)[row * 128 + (col - 256)] = f2bf(v);
        } else {
          size_t idx = (size_t)(rbase + r) * N + col;
          if (OMODE == 3) {
            ((float*)Cout)[idx] = v + res[idx];
          } else {
            ((unsigned short*)Cout)[idx] = f2bf(v);
          }
        }
      }
    }
  }
}

// ---------------- deformable sampling + fused softmax ----------------
// Wave-per-query: 4 queries/block, NO __syncthreads (wave-synchronous LDS).
// Phase 1: lane handles units u=2*lane, 2*lane+1 (same (h,level) pair).
//   softmax over each head's 16 logits lives in 8 lanes (2/lane): 3-level
//   shfl_xor butterflies. Byte-scaled clamped flat indices + prescaled
//   masked bilinear weights -> LDS as [pt][h ^ (pt&7)][4] (XOR swizzle +
//   int4/float4 stores -> near-conflict-free b128 writes).
// Phase 2: lane = (h, g): g = 4-channel group; lane accumulates ALL 16
//   points for its channels via VOP3P op_sel packed FMA (weight pair is a
//   subregister of the ds_read_b128 float4 -> zero broadcast movs).
__global__ __launch_bounds__(256) void deform_sample(
    const unsigned short* __restrict__ val, const unsigned short* __restrict__ off,
    const unsigned short* __restrict__ logits, const float* __restrict__ refp,
    unsigned short* __restrict__ out) {
  __shared__ __attribute__((aligned(16))) int sIdx[4][16][8][4];
  __shared__ __attribute__((aligned(16))) float sW[4][16][8][4];
  const int w = threadIdx.x >> 6, lane = threadIdx.x & 63;
  const int bq = blockIdx.x * 4 + w;
  const int b = __builtin_amdgcn_readfirstlane(bq / LQTOK);
  {
    const int HW_[4] = {128, 64, 32, 16};
    const int LSI_[4] = {0, 16384, 20480, 21504};
    int u0 = 2 * lane;
    int h = u0 >> 4;
    int lvl = (u0 >> 2) & 3;
    int pt0 = u0 & 15;
    int HW = HW_[lvl];
    float2 rp = ((const float2*)refp)[(size_t)bq * 4 + lvl];
    uint2 ov = *(const uint2*)(off + (size_t)bq * 256 + 4 * lane);
    unsigned int lgu = *(const unsigned int*)(logits + (size_t)bq * 128 + 2 * lane);
    float lg0 = bflo(lgu), lg1 = bfhi(lgu);
    // fused softmax over this head's 16 logits (8 lanes x 2)
    float mx = fmaxf(lg0, lg1);
#pragma unroll
    for (int s = 1; s < 8; s <<= 1) mx = fmaxf(mx, __shfl_xor(mx, s, 64));
    float e0 = expf(lg0 - mx), e1 = expf(lg1 - mx);
    float es = e0 + e1;
#pragma unroll
    for (int s = 1; s < 8; s <<= 1) es += __shfl_xor(es, s, 64);
    float inv = 1.0f / es;
    float a01[2] = {e0 * inv, e1 * inv};
    unsigned int ovv[2] = {ov.x, ov.y};
    int hb2 = h * (DHEAD * 2);  // head byte offset
#pragma unroll
    for (int c = 0; c < 2; c++) {
      float x = fmaf(rp.x, (float)HW, bflo(ovv[c])) - 0.5f;
      float y = fmaf(rp.y, (float)HW, bfhi(ovv[c])) - 0.5f;
      float xf = floorf(x), yf = floorf(y);
      int x0 = (int)xf, y0 = (int)yf;
      float lx = x - xf, ly = y - yf;
      int x0c = min(max(x0, 0), HW - 1);
      int x1c = min(max(x0 + 1, 0), HW - 1);
      int y0c = min(max(y0, 0), HW - 1);
      int y1c = min(max(y0 + 1, 0), HW - 1);
      float m0x = (x0 >= 0 && x0 < HW) ? 1.f : 0.f;
      float m1x = (x0 + 1 >= 0 && x0 + 1 < HW) ? 1.f : 0.f;
      float m0y = (y0 >= 0 && y0 < HW) ? 1.f : 0.f;
      float m1y = (y0 + 1 >= 0 && y0 + 1 < HW) ? 1.f : 0.f;
      float a = a01[c];
      int pt = pt0 + c;
      int hs = h ^ (pt & 7);
      int r0 = (LSI_[lvl] + y0c * HW) * (DMODEL * 2) + hb2;
      int r1 = (LSI_[lvl] + y1c * HW) * (DMODEL * 2) + hb2;
      *(int4*)sIdx[w][pt][hs] =
          make_int4(r0 + x0c * (DMODEL * 2), r0 + x1c * (DMODEL * 2),
                    r1 + x0c * (DMODEL * 2), r1 + x1c * (DMODEL * 2));
      *(float4*)sW[w][pt][hs] =
          make_float4((1.f - lx) * (1.f - ly) * m0x * m0y * a,
                      lx * (1.f - ly) * m1x * m0y * a,
                      (1.f - lx) * ly * m0x * m1y * a,
                      lx * ly * m1x * m1y * a);
    }
  }
  // wave-synchronous handoff: same wave wrote, same wave reads.
  __builtin_amdgcn_wave_barrier();
  const int h2 = lane >> 3, g = lane & 7;
  const char* basep =
      (const char*)val + (size_t)b * ((size_t)LQTOK * DMODEL * 2);
  const int goff = g * 8;  // byte offset of this lane's 4-channel group
  f32x2 a01v = {0.f, 0.f}, a23v = {0.f, 0.f};
#pragma unroll
  for (int pb = 0; pb < 4; pb++) {
    int4 ix[4];
    f32x4 wt4[4];
#pragma unroll
    for (int p = 0; p < 4; p++) {
      int pt = pb * 4 + p;
      int hs = h2 ^ (pt & 7);
      ix[p] = *(const int4*)sIdx[w][pt][hs];
      wt4[p] = *(const f32x4*)sW[w][pt][hs];
    }
    uint2 v4[4][4];
#pragma unroll
    for (int p = 0; p < 4; p++) {
      v4[p][0] = *(const uint2*)(basep + (unsigned)(ix[p].x + goff));
      v4[p][1] = *(const uint2*)(basep + (unsigned)(ix[p].y + goff));
      v4[p][2] = *(const uint2*)(basep + (unsigned)(ix[p].z + goff));
      v4[p][3] = *(const uint2*)(basep + (unsigned)(ix[p].w + goff));
    }
#pragma unroll
    for (int p = 0; p < 4; p++) {
      f32x2 w01 = __builtin_shufflevector(wt4[p], wt4[p], 0, 1);
      f32x2 w23 = __builtin_shufflevector(wt4[p], wt4[p], 2, 3);
#pragma unroll
      for (int k = 0; k < 4; k++) {
        uint2 u = v4[p][k];
        f32x2 vlo, vhi;
        vlo[0] = bflo(u.x);
        vlo[1] = bfhi(u.x);
        vhi[0] = bflo(u.y);
        vhi[1] = bfhi(u.y);
        f32x2 wp = (k < 2) ? w01 : w23;
        if ((k & 1) == 0) {
          pk_fma_blo(a01v, vlo, wp);
          pk_fma_blo(a23v, vhi, wp);
        } else {
          pk_fma_bhi(a01v, vlo, wp);
          pk_fma_bhi(a23v, vhi, wp);
        }
      }
    }
  }
  unsigned int o0 = ((unsigned int)f2bf(a01v[1]) << 16) | f2bf(a01v[0]);
  unsigned int o1 = ((unsigned int)f2bf(a23v[1]) << 16) | f2bf(a23v[0]);
  *(uint2*)(out + (size_t)bq * 256 + h2 * 32 + g * 4) = make_uint2(o0, o1);
}

// ---------------- launch ----------------
extern "C" void kernel_launch(void* const* d_in, const int* in_sizes, int n_in,
                              void* d_out, int out_size, void* d_ws,
                              size_t ws_size, hipStream_t stream) {
  const float* src    = (const float*)d_in[0];
  const float* pos    = (const float*)d_in[1];
  const float* refp   = (const float*)d_in[2];
  const float* g1     = (const float*)d_in[5];
  const float* beta1  = (const float*)d_in[6];
  const float* w_off  = (const float*)d_in[7];
  const float* b_off  = (const float*)d_in[8];
  const float* w_attn = (const float*)d_in[9];
  const float* b_attn = (const float*)d_in[10];
  const float* w_val  = (const float*)d_in[11];
  const float* b_val  = (const float*)d_in[12];
  const float* w_out  = (const float*)d_in[13];
  const float* b_out  = (const float*)d_in[14];
  const float* g2     = (const float*)d_in[15];
  const float* beta2  = (const float*)d_in[16];
  const float* w_fc1  = (const float*)d_in[17];
  const float* b_fc1  = (const float*)d_in[18];
  const float* w_fc2  = (const float*)d_in[19];
  const float* b_fc2  = (const float*)d_in[20];
  float* out = (float*)d_out;

  // Workspace layout (byte budget identical to the verified baseline):
  //  b1..b4 (4 x 22.28MB, contiguous) double as the full FFN hidden (89.1MB)
  //  b5 (44.6MB) holds logits bf16 then y bf16; src2 goes straight to d_out.
  const size_t NT = (size_t)NTOK;
  unsigned short* b1 = (unsigned short*)d_ws;  // x bf16 -> sampled -> hid
  unsigned short* b2 = b1 + NT * 256;          // val bf16          -> hid
  unsigned short* b3 = b2 + NT * 256;          // off bf16          -> hid
  unsigned short* b4 = b3 + NT * 256;          // q bf16            -> hid
  unsigned short* b5 = b4 + NT * 256;          // logits bf16 -> y bf16
  unsigned short* wvalT  = b5 + NT * 512;      // [256][256]
  unsigned short* woffaT = wvalT + 256 * 256;  // [384][256] (off|attn merged)
  unsigned short* woutT  = woffaT + 384 * 256; // [256][256]
  unsigned short* wfc1T  = woutT + 256 * 256;  // [1024][256]
  unsigned short* wfc2T  = wfc1T + 1024 * 256; // [256][1024]

  unsigned short* qb  = b4;  // q = x+pos, bf16 [NT][256]
  unsigned short* lgb = b5;  // logits bf16 [NT][128]
  unsigned short* yb  = b5;  // y bf16 [NT][256] (after logits dead)
  unsigned short* hid = b1;  // FFN hidden bf16 [NT][1024] spans b1..b4

  // 0. weight transposes (f32 -> bf16, [K][N] -> [N][K])
  transpose_bf16<<<dim3(8, 8), 256, 0, stream>>>(w_val, wvalT, 256, 256);
  transpose_bf16<<<dim3(8, 8), 256, 0, stream>>>(w_off, woffaT, 256, 256);
  transpose_bf16<<<dim3(8, 4), 256, 0, stream>>>(w_attn, woffaT + 256 * 256,
                                                 256, 128);
  transpose_bf16<<<dim3(8, 8), 256, 0, stream>>>(w_out, woutT, 256, 256);
  transpose_bf16<<<dim3(8, 32), 256, 0, stream>>>(w_fc1, wfc1T, 256, 1024);
  transpose_bf16<<<dim3(32, 8), 256, 0, stream>>>(w_fc2, wfc2T, 1024, 256);

  const int MT = NTOK / 128;  // 340

  // 1. x = LN(src) -> b1 (bf16); q = bf16(x)+pos -> qb (bf16)
  ln_bf16<true><<<NTOK / 4, 256, 0, stream>>>(src, g1, beta1, b1, pos, qb);
  // 2. val = x @ w_val + b_val -> b2 (bf16)
  gemm_mfma<1><<<dim3(MT, 2), 256, 0, stream>>>(b1, wvalT, b_val, nullptr, b2,
                                                nullptr, NTOK, 256, 256);
  // 3. [off | logits] = q @ [w_off | w_attn] (one pass over q, N=384)
  gemm_mfma<4><<<dim3(MT, 3), 256, 0, stream>>>(qb, woffaT, b_off, b_attn, b3,
                                                lgb, NTOK, 384, 256);
  // 4. sampling (fused softmax) -> b1 (x dead, q dead)
  deform_sample<<<NTOK / 4, 256, 0, stream>>>(b2, b3, lgb, refp, b1);
  // 5. src2 = sampled @ w_out + b_out + src -> d_out (f32)
  gemm_mfma<3><<<dim3(MT, 2), 256, 0, stream>>>(b1, woutT, b_out, src, out,
                                                nullptr, NTOK, 256, 256);
  // 6. y = LN(src2) -> yb (bf16; overwrites dead logits)
  ln_bf16<false><<<NTOK / 4, 256, 0, stream>>>(out, g2, beta2, yb, nullptr,
                                               nullptr);
  // 7. hid = relu(y @ w_fc1 + b_fc1) -> b1..b4 (89.1MB, all dead)
  gemm_mfma<2><<<dim3(MT, 8), 256, 0, stream>>>(yb, wfc1T, b_fc1, nullptr, hid,
                                                nullptr, NTOK, 1024, 256);
  // 8. out = hid @ w_fc2 + b_fc2 + src2(d_out) -> d_out (read-then-write)
  gemm_mfma<3><<<dim3(MT, 2), 256, 0, stream>>>(hid, wfc2T, b_fc2, out, out,
                                                nullptr, NTOK, 256, 1024);
}

// Round 5
// 415.043 us; speedup vs baseline: 1.2891x; 1.0549x over previous
//
#include <hip/hip_runtime.h>

// MSDeformAttn encoder layer — bf16 MFMA GEMMs (global_load_lds staging,
// XCD-chunked block swizzle, fused dispatches) + wave-per-query deformable
// sampling with fused softmax (no barriers, op_sel packed-FMA).
#define DMODEL 256
#define NHEAD 8
#define NPOINT 4
#define NLEVEL 4
#define DHEAD 32
#define MLPD 1024
#define BSZ 2
#define LQTOK 21760
#define NTOK (BSZ * LQTOK)  // 43520
#define LNEPS 1e-6f

typedef __attribute__((ext_vector_type(8))) short short8;
typedef __attribute__((ext_vector_type(4))) float f32x4;
typedef __attribute__((ext_vector_type(2))) float f32x2;

__device__ __forceinline__ float bf2f(unsigned short u) {
  unsigned int i = ((unsigned int)u) << 16;
  return __builtin_bit_cast(float, i);
}
__device__ __forceinline__ unsigned short f2bf(float f) {
  unsigned int i = __builtin_bit_cast(unsigned int, f);
  i += 0x7fff + ((i >> 16) & 1);  // round-to-nearest-even
  return (unsigned short)(i >> 16);
}
__device__ __forceinline__ float bflo(unsigned int u) {
  return __builtin_bit_cast(float, u << 16);
}
__device__ __forceinline__ float bfhi(unsigned int u) {
  return __builtin_bit_cast(float, u & 0xffff0000u);
}

// d += a * b.lo (both halves use word0 of b)   [VOP3P: all srcs are pairs]
__device__ __forceinline__ void pk_fma_blo(f32x2& d, f32x2 a, f32x2 b) {
  asm("v_pk_fma_f32 %0, %1, %2, %0 op_sel:[0,0,0] op_sel_hi:[1,0,1]"
      : "+v"(d)
      : "v"(a), "v"(b));
}
// d += a * b.hi (both halves use word1 of b)
__device__ __forceinline__ void pk_fma_bhi(f32x2& d, f32x2 a, f32x2 b) {
  asm("v_pk_fma_f32 %0, %1, %2, %0 op_sel:[0,1,0] op_sel_hi:[1,1,1]"
      : "+v"(d)
      : "v"(a), "v"(b));
}

// async global->LDS, 16B per lane; lds dest = wave-uniform base + lane*16
__device__ __forceinline__ void gload_lds16(const unsigned short* g,
                                            unsigned short* lds) {
  __builtin_amdgcn_global_load_lds(
      (const __attribute__((address_space(1))) unsigned int*)g,
      (__attribute__((address_space(3))) unsigned int*)lds, 16, 0, 0);
}

// bijective XCD-chunked block swizzle (m204): consecutive wgid stay on one
// XCD and iterate the column index fastest -> A-panel L2 reuse.
__device__ __forceinline__ unsigned xcd_swz(unsigned orig, unsigned nwg) {
  unsigned xcd = orig & 7u, rest = orig >> 3;
  unsigned qq = nwg >> 3, rr = nwg & 7u;
  return (xcd < rr ? xcd * (qq + 1) : rr * (qq + 1) + (xcd - rr) * qq) + rest;
}

// ---------------- layernorm: wave-per-row, no LDS/barriers -----------------
// o = bf16(LN(in)*g + beta); if EMITQ also q = bf16(bf2f(o) + pos)
template <bool EMITQ>
__global__ __launch_bounds__(256) void ln_bf16(
    const float* __restrict__ in, const float* __restrict__ g,
    const float* __restrict__ beta, unsigned short* __restrict__ o,
    const float* __restrict__ pos, unsigned short* __restrict__ q) {
  const int w = threadIdx.x >> 6, lane = threadIdx.x & 63;
  const size_t t = (size_t)blockIdx.x * 4 + w;
  const size_t base = t * DMODEL + lane * 4;
  float4 v = *(const float4*)(in + base);
  float s = (v.x + v.y) + (v.z + v.w);
#pragma unroll
  for (int off = 32; off; off >>= 1) s += __shfl_xor(s, off, 64);
  float mu = s * (1.0f / DMODEL);
  float dx = v.x - mu, dy = v.y - mu, dz = v.z - mu, dw = v.w - mu;
  float s2 = (dx * dx + dy * dy) + (dz * dz + dw * dw);
#pragma unroll
  for (int off = 32; off; off >>= 1) s2 += __shfl_xor(s2, off, 64);
  float rs = rsqrtf(s2 * (1.0f / DMODEL) + LNEPS);
  float4 gg = *(const float4*)(g + lane * 4);
  float4 bb = *(const float4*)(beta + lane * 4);
  unsigned short r0 = f2bf(dx * rs * gg.x + bb.x);
  unsigned short r1 = f2bf(dy * rs * gg.y + bb.y);
  unsigned short r2 = f2bf(dz * rs * gg.z + bb.z);
  unsigned short r3 = f2bf(dw * rs * gg.w + bb.w);
  unsigned int lo = ((unsigned int)r1 << 16) | r0;
  unsigned int hi = ((unsigned int)r3 << 16) | r2;
  *(uint2*)(o + base) = make_uint2(lo, hi);
  if (EMITQ) {
    float4 p = *(const float4*)(pos + base);
    unsigned short q0 = f2bf(bf2f(r0) + p.x);
    unsigned short q1 = f2bf(bf2f(r1) + p.y);
    unsigned short q2 = f2bf(bf2f(r2) + p.z);
    unsigned short q3 = f2bf(bf2f(r3) + p.w);
    unsigned int ql = ((unsigned int)q1 << 16) | q0;
    unsigned int qh = ((unsigned int)q3 << 16) | q2;
    *(uint2*)(q + base) = make_uint2(ql, qh);
  }
}

// ------ all weight transposes in ONE dispatch: Wt[n][k] = bf16(W[k][n]) ----
// block ranges: [0,64) val | [64,128) off | [128,160) attn | [160,224) out |
// [224,480) fc1 | [480,736) fc2
__global__ __launch_bounds__(256) void transpose_all(
    const float* __restrict__ w_val, const float* __restrict__ w_off,
    const float* __restrict__ w_attn, const float* __restrict__ w_out,
    const float* __restrict__ w_fc1, const float* __restrict__ w_fc2,
    unsigned short* __restrict__ wvalT, unsigned short* __restrict__ woffaT,
    unsigned short* __restrict__ woutT, unsigned short* __restrict__ wfc1T,
    unsigned short* __restrict__ wfc2T) {
  __shared__ float tile[32][33];
  int bid = blockIdx.x;
  const float* W;
  unsigned short* Wt;
  int K, N, rel;
  if (bid < 64) {
    W = w_val; Wt = wvalT; K = 256; N = 256; rel = bid;
  } else if (bid < 128) {
    W = w_off; Wt = woffaT; K = 256; N = 256; rel = bid - 64;
  } else if (bid < 160) {
    W = w_attn; Wt = woffaT + 256 * 256; K = 256; N = 128; rel = bid - 128;
  } else if (bid < 224) {
    W = w_out; Wt = woutT; K = 256; N = 256; rel = bid - 160;
  } else if (bid < 480) {
    W = w_fc1; Wt = wfc1T; K = 256; N = 1024; rel = bid - 224;
  } else {
    W = w_fc2; Wt = wfc2T; K = 1024; N = 256; rel = bid - 480;
  }
  int ktiles = K >> 5;
  int k0 = (rel % ktiles) * 32, n0 = (rel / ktiles) * 32;
  int tx = threadIdx.x & 31, ty = threadIdx.x >> 5;  // 32 x 8
  for (int i = ty; i < 32; i += 8)
    tile[i][tx] = W[(size_t)(k0 + i) * N + n0 + tx];
  __syncthreads();
  for (int i = ty; i < 32; i += 8)
    Wt[(size_t)(n0 + i) * K + k0 + tx] = f2bf(tile[tx][i]);
}

// ---------------- bf16 MFMA GEMM core (m97 structure) ----------------------
// Tile 128x128, BK=32, 256 threads = 4 waves (2x2 of 64x64), 4x4 MFMA
// 16x16x32 per wave. A: bf16 [M][K]. Wt: bf16 [N][K]. Unpadded pitch-32 LDS
// (required by global_load_lds).
// OMODE: 2=bf16+relu, 3=f32+res.
template <int OMODE>
__global__ __launch_bounds__(256) void gemm_mfma(
    const unsigned short* __restrict__ A, const unsigned short* __restrict__ Wt,
    const float* __restrict__ bias, const float* __restrict__ res,
    void* __restrict__ Cout, int M, int N, int K) {
  __shared__ __attribute__((aligned(16))) unsigned short As[128 * 32];
  __shared__ __attribute__((aligned(16))) unsigned short Bs[128 * 32];
  const int tid = threadIdx.x;
  const unsigned gy = gridDim.y;
  const unsigned wgid = xcd_swz(blockIdx.y * gridDim.x + blockIdx.x,
                                gridDim.x * gy);
  const int m0 = (int)(wgid / gy) * 128;
  const int n0 = (int)(wgid % gy) * 128;
  const int wave = tid >> 6, lane = tid & 63;
  const int wm = (wave & 1) * 64, wn = (wave >> 1) * 64;
  const int lr = lane & 15, quad = lane >> 4;
  f32x4 acc[4][4] = {};
  for (int k0 = 0; k0 < K; k0 += 32) {
    __syncthreads();
#pragma unroll
    for (int r = 0; r < 2; r++) {
      int c = r * 256 + tid;
      int row = c >> 2, col8 = (c & 3) * 8;
      gload_lds16(Wt + (size_t)(n0 + row) * K + k0 + col8,
                  &Bs[(r * 256 + wave * 64) * 8]);
    }
#pragma unroll
    for (int r = 0; r < 2; r++) {
      int c = r * 256 + tid;
      int row = c >> 2, col8 = (c & 3) * 8;
      gload_lds16(A + (size_t)(m0 + row) * K + k0 + col8,
                  &As[(r * 256 + wave * 64) * 8]);
    }
    __syncthreads();
    short8 af[4], bfr[4];
#pragma unroll
    for (int i = 0; i < 4; i++)
      af[i] = *(const short8*)(&As[(wm + i * 16 + lr) * 32 + quad * 8]);
#pragma unroll
    for (int j = 0; j < 4; j++)
      bfr[j] = *(const short8*)(&Bs[(wn + j * 16 + lr) * 32 + quad * 8]);
#pragma unroll
    for (int i = 0; i < 4; i++)
#pragma unroll
      for (int j = 0; j < 4; j++)
        acc[i][j] = __builtin_amdgcn_mfma_f32_16x16x32_bf16(af[i], bfr[j],
                                                            acc[i][j], 0, 0, 0);
  }
  // epilogue: C/D layout col=lane&15, row=quad*4+reg
#pragma unroll
  for (int i = 0; i < 4; i++) {
    int rbase = m0 + wm + i * 16 + quad * 4;
#pragma unroll
    for (int j = 0; j < 4; j++) {
      int col = n0 + wn + j * 16 + lr;
      float bv = bias[col];
#pragma unroll
      for (int r = 0; r < 4; r++) {
        size_t idx = (size_t)(rbase + r) * N + col;
        float v = acc[i][j][r] + bv;
        if (OMODE == 2) v = fmaxf(v, 0.0f);
        if (OMODE == 3) {
          ((float*)Cout)[idx] = v + res[idx];
        } else {
          ((unsigned short*)Cout)[idx] = f2bf(v);
        }
      }
    }
  }
}

// ---- fused val + off|attn GEMM: one dispatch, grid (340, 5) ----
// column-role: ny<2 -> val = x @ w_val (A=xb), ny>=2 -> [off|logits] = q @
// [w_off|w_attn] (A=qb). Both K=256.
__global__ __launch_bounds__(256) void gemm_vo(
    const unsigned short* __restrict__ Ax, const unsigned short* __restrict__ Aq,
    const unsigned short* __restrict__ Wval,
    const unsigned short* __restrict__ Woa, const float* __restrict__ bval,
    const float* __restrict__ boff, const float* __restrict__ battn,
    unsigned short* __restrict__ oval, unsigned short* __restrict__ ooff,
    unsigned short* __restrict__ olg) {
  __shared__ __attribute__((aligned(16))) unsigned short As[128 * 32];
  __shared__ __attribute__((aligned(16))) unsigned short Bs[128 * 32];
  const int tid = threadIdx.x;
  const unsigned gy = gridDim.y;  // 5
  const unsigned wgid = xcd_swz(blockIdx.y * gridDim.x + blockIdx.x,
                                gridDim.x * gy);
  const int m0 = (int)(wgid / gy) * 128;
  const int ny = (int)(wgid % gy);
  const bool isval = ny < 2;
  const unsigned short* A = isval ? Ax : Aq;
  const unsigned short* Wt = isval ? Wval : Woa;
  const int n0 = isval ? ny * 128 : (ny - 2) * 128;
  const int wave = tid >> 6, lane = tid & 63;
  const int wm = (wave & 1) * 64, wn = (wave >> 1) * 64;
  const int lr = lane & 15, quad = lane >> 4;
  f32x4 acc[4][4] = {};
  for (int k0 = 0; k0 < 256; k0 += 32) {
    __syncthreads();
#pragma unroll
    for (int r = 0; r < 2; r++) {
      int c = r * 256 + tid;
      int row = c >> 2, col8 = (c & 3) * 8;
      gload_lds16(Wt + (size_t)(n0 + row) * 256 + k0 + col8,
                  &Bs[(r * 256 + wave * 64) * 8]);
    }
#pragma unroll
    for (int r = 0; r < 2; r++) {
      int c = r * 256 + tid;
      int row = c >> 2, col8 = (c & 3) * 8;
      gload_lds16(A + (size_t)(m0 + row) * 256 + k0 + col8,
                  &As[(r * 256 + wave * 64) * 8]);
    }
    __syncthreads();
    short8 af[4], bfr[4];
#pragma unroll
    for (int i = 0; i < 4; i++)
      af[i] = *(const short8*)(&As[(wm + i * 16 + lr) * 32 + quad * 8]);
#pragma unroll
    for (int j = 0; j < 4; j++)
      bfr[j] = *(const short8*)(&Bs[(wn + j * 16 + lr) * 32 + quad * 8]);
#pragma unroll
    for (int i = 0; i < 4; i++)
#pragma unroll
      for (int j = 0; j < 4; j++)
        acc[i][j] = __builtin_amdgcn_mfma_f32_16x16x32_bf16(af[i], bfr[j],
                                                            acc[i][j], 0, 0, 0);
  }
#pragma unroll
  for (int i = 0; i < 4; i++) {
    int rbase = m0 + wm + i * 16 + quad * 4;
#pragma unroll
    for (int j = 0; j < 4; j++) {
      int col = n0 + wn + j * 16 + lr;
      float bv = isval ? bval[col]
                       : (col < 256 ? boff[col] : battn[col - 256]);
#pragma unroll
      for (int r = 0; r < 4; r++) {
        size_t row = (size_t)(rbase + r);
        float v = acc[i][j][r] + bv;
        if (isval) {
          oval[row * 256 + col] = f2bf(v);
        } else if (col < 256) {
          ooff[row * 256 + col] = f2bf(v);
        } else {
          olg[row * 128 + (col - 256)] = f2bf(v);
        }
      }
    }
  }
}

// ---------------- deformable sampling + fused softmax ----------------
// Wave-per-query: 8 queries/block (512 thr), NO __syncthreads.
// Phase 1: lane handles units u=2*lane, 2*lane+1 (same (h,level) pair).
//   softmax over each head's 16 logits lives in 8 lanes (2/lane): 3-level
//   shfl_xor butterflies. Byte-scaled clamped flat indices + prescaled
//   masked bilinear weights -> LDS as [pt][h ^ (pt&7)][4] (XOR swizzle +
//   int4/float4 stores -> near-conflict-free b128 writes).
// Phase 2: lane = (h, g): g = 4-channel group; lane accumulates ALL 16
//   points for its channels via VOP3P op_sel packed FMA (weight pair is a
//   subregister of the ds_read_b128 float4 -> zero broadcast movs).
__global__ __launch_bounds__(512) void deform_sample(
    const unsigned short* __restrict__ val, const unsigned short* __restrict__ off,
    const unsigned short* __restrict__ logits, const float* __restrict__ refp,
    unsigned short* __restrict__ out) {
  __shared__ __attribute__((aligned(16))) int sIdx[8][16][8][4];
  __shared__ __attribute__((aligned(16))) float sW[8][16][8][4];
  const int w = threadIdx.x >> 6, lane = threadIdx.x & 63;
  const int bq = blockIdx.x * 8 + w;
  const int b = __builtin_amdgcn_readfirstlane(bq / LQTOK);
  {
    const int HW_[4] = {128, 64, 32, 16};
    const int LSI_[4] = {0, 16384, 20480, 21504};
    int u0 = 2 * lane;
    int h = u0 >> 4;
    int lvl = (u0 >> 2) & 3;
    int pt0 = u0 & 15;
    int HW = HW_[lvl];
    float2 rp = ((const float2*)refp)[(size_t)bq * 4 + lvl];
    uint2 ov = *(const uint2*)(off + (size_t)bq * 256 + 4 * lane);
    unsigned int lgu = *(const unsigned int*)(logits + (size_t)bq * 128 + 2 * lane);
    float lg0 = bflo(lgu), lg1 = bfhi(lgu);
    // fused softmax over this head's 16 logits (8 lanes x 2)
    float mx = fmaxf(lg0, lg1);
#pragma unroll
    for (int s = 1; s < 8; s <<= 1) mx = fmaxf(mx, __shfl_xor(mx, s, 64));
    float e0 = expf(lg0 - mx), e1 = expf(lg1 - mx);
    float es = e0 + e1;
#pragma unroll
    for (int s = 1; s < 8; s <<= 1) es += __shfl_xor(es, s, 64);
    float inv = 1.0f / es;
    float a01[2] = {e0 * inv, e1 * inv};
    unsigned int ovv[2] = {ov.x, ov.y};
    int hb2 = h * (DHEAD * 2);  // head byte offset
#pragma unroll
    for (int c = 0; c < 2; c++) {
      float x = fmaf(rp.x, (float)HW, bflo(ovv[c])) - 0.5f;
      float y = fmaf(rp.y, (float)HW, bfhi(ovv[c])) - 0.5f;
      float xf = floorf(x), yf = floorf(y);
      int x0 = (int)xf, y0 = (int)yf;
      float lx = x - xf, ly = y - yf;
      int x0c = min(max(x0, 0), HW - 1);
      int x1c = min(max(x0 + 1, 0), HW - 1);
      int y0c = min(max(y0, 0), HW - 1);
      int y1c = min(max(y0 + 1, 0), HW - 1);
      float m0x = (x0 >= 0 && x0 < HW) ? 1.f : 0.f;
      float m1x = (x0 + 1 >= 0 && x0 + 1 < HW) ? 1.f : 0.f;
      float m0y = (y0 >= 0 && y0 < HW) ? 1.f : 0.f;
      float m1y = (y0 + 1 >= 0 && y0 + 1 < HW) ? 1.f : 0.f;
      float a = a01[c];
      int pt = pt0 + c;
      int hs = h ^ (pt & 7);
      int r0 = (LSI_[lvl] + y0c * HW) * (DMODEL * 2) + hb2;
      int r1 = (LSI_[lvl] + y1c * HW) * (DMODEL * 2) + hb2;
      *(int4*)sIdx[w][pt][hs] =
          make_int4(r0 + x0c * (DMODEL * 2), r0 + x1c * (DMODEL * 2),
                    r1 + x0c * (DMODEL * 2), r1 + x1c * (DMODEL * 2));
      *(float4*)sW[w][pt][hs] =
          make_float4((1.f - lx) * (1.f - ly) * m0x * m0y * a,
                      lx * (1.f - ly) * m1x * m0y * a,
                      (1.f - lx) * ly * m0x * m1y * a,
                      lx * ly * m1x * m1y * a);
    }
  }
  // wave-synchronous handoff: same wave wrote, same wave reads.
  __builtin_amdgcn_wave_barrier();
  const int h2 = lane >> 3, g = lane & 7;
  const char* basep =
      (const char*)val + (size_t)b * ((size_t)LQTOK * DMODEL * 2);
  const int goff = g * 8;  // byte offset of this lane's 4-channel group
  f32x2 a01v = {0.f, 0.f}, a23v = {0.f, 0.f};
#pragma unroll
  for (int pb = 0; pb < 4; pb++) {
    int4 ix[4];
    f32x4 wt4[4];
#pragma unroll
    for (int p = 0; p < 4; p++) {
      int pt = pb * 4 + p;
      int hs = h2 ^ (pt & 7);
      ix[p] = *(const int4*)sIdx[w][pt][hs];
      wt4[p] = *(const f32x4*)sW[w][pt][hs];
    }
    uint2 v4[4][4];
#pragma unroll
    for (int p = 0; p < 4; p++) {
      v4[p][0] = *(const uint2*)(basep + (unsigned)(ix[p].x + goff));
      v4[p][1] = *(const uint2*)(basep + (unsigned)(ix[p].y + goff));
      v4[p][2] = *(const uint2*)(basep + (unsigned)(ix[p].z + goff));
      v4[p][3] = *(const uint2*)(basep + (unsigned)(ix[p].w + goff));
    }
#pragma unroll
    for (int p = 0; p < 4; p++) {
      f32x2 w01 = __builtin_shufflevector(wt4[p], wt4[p], 0, 1);
      f32x2 w23 = __builtin_shufflevector(wt4[p], wt4[p], 2, 3);
#pragma unroll
      for (int k = 0; k < 4; k++) {
        uint2 u = v4[p][k];
        f32x2 vlo, vhi;
        vlo[0] = bflo(u.x);
        vlo[1] = bfhi(u.x);
        vhi[0] = bflo(u.y);
        vhi[1] = bfhi(u.y);
        f32x2 wp = (k < 2) ? w01 : w23;
        if ((k & 1) == 0) {
          pk_fma_blo(a01v, vlo, wp);
          pk_fma_blo(a23v, vhi, wp);
        } else {
          pk_fma_bhi(a01v, vlo, wp);
          pk_fma_bhi(a23v, vhi, wp);
        }
      }
    }
  }
  unsigned int o0 = ((unsigned int)f2bf(a01v[1]) << 16) | f2bf(a01v[0]);
  unsigned int o1 = ((unsigned int)f2bf(a23v[1]) << 16) | f2bf(a23v[0]);
  *(uint2*)(out + (size_t)bq * 256 + h2 * 32 + g * 4) = make_uint2(o0, o1);
}

// ---------------- launch ----------------
extern "C" void kernel_launch(void* const* d_in, const int* in_sizes, int n_in,
                              void* d_out, int out_size, void* d_ws,
                              size_t ws_size, hipStream_t stream) {
  const float* src    = (const float*)d_in[0];
  const float* pos    = (const float*)d_in[1];
  const float* refp   = (const float*)d_in[2];
  const float* g1     = (const float*)d_in[5];
  const float* beta1  = (const float*)d_in[6];
  const float* w_off  = (const float*)d_in[7];
  const float* b_off  = (const float*)d_in[8];
  const float* w_attn = (const float*)d_in[9];
  const float* b_attn = (const float*)d_in[10];
  const float* w_val  = (const float*)d_in[11];
  const float* b_val  = (const float*)d_in[12];
  const float* w_out  = (const float*)d_in[13];
  const float* b_out  = (const float*)d_in[14];
  const float* g2     = (const float*)d_in[15];
  const float* beta2  = (const float*)d_in[16];
  const float* w_fc1  = (const float*)d_in[17];
  const float* b_fc1  = (const float*)d_in[18];
  const float* w_fc2  = (const float*)d_in[19];
  const float* b_fc2  = (const float*)d_in[20];
  float* out = (float*)d_out;

  // Workspace layout (byte budget identical to the verified baseline):
  //  b1..b4 (4 x 22.28MB, contiguous) double as the full FFN hidden (89.1MB)
  //  b5 (44.6MB) holds logits bf16 then y bf16; src2 goes straight to d_out.
  const size_t NT = (size_t)NTOK;
  unsigned short* b1 = (unsigned short*)d_ws;  // x bf16 -> sampled -> hid
  unsigned short* b2 = b1 + NT * 256;          // val bf16          -> hid
  unsigned short* b3 = b2 + NT * 256;          // off bf16          -> hid
  unsigned short* b4 = b3 + NT * 256;          // q bf16            -> hid
  unsigned short* b5 = b4 + NT * 256;          // logits bf16 -> y bf16
  unsigned short* wvalT  = b5 + NT * 512;      // [256][256]
  unsigned short* woffaT = wvalT + 256 * 256;  // [384][256] (off|attn merged)
  unsigned short* woutT  = woffaT + 384 * 256; // [256][256]
  unsigned short* wfc1T  = woutT + 256 * 256;  // [1024][256]
  unsigned short* wfc2T  = wfc1T + 1024 * 256; // [256][1024]

  unsigned short* qb  = b4;  // q = x+pos, bf16 [NT][256]
  unsigned short* lgb = b5;  // logits bf16 [NT][128]
  unsigned short* yb  = b5;  // y bf16 [NT][256] (after logits dead)
  unsigned short* hid = b1;  // FFN hidden bf16 [NT][1024] spans b1..b4

  const int MT = NTOK / 128;  // 340

  // 0. all weight transposes (f32 -> bf16, [K][N] -> [N][K]) in ONE dispatch
  transpose_all<<<736, 256, 0, stream>>>(w_val, w_off, w_attn, w_out, w_fc1,
                                         w_fc2, wvalT, woffaT, woutT, wfc1T,
                                         wfc2T);
  // 1. x = LN(src) -> b1 (bf16); q = bf16(x)+pos -> qb (bf16)
  ln_bf16<true><<<NTOK / 4, 256, 0, stream>>>(src, g1, beta1, b1, pos, qb);
  // 2. fused: val = x @ w_val + b_val -> b2 ; [off|logits] = q @ woffa -> b3,lgb
  gemm_vo<<<dim3(MT, 5), 256, 0, stream>>>(b1, qb, wvalT, woffaT, b_val, b_off,
                                           b_attn, b2, b3, lgb);
  // 3. sampling (fused softmax) -> b1 (x dead, q dead)
  deform_sample<<<NTOK / 8, 512, 0, stream>>>(b2, b3, lgb, refp, b1);
  // 4. src2 = sampled @ w_out + b_out + src -> d_out (f32)
  gemm_mfma<3><<<dim3(MT, 2), 256, 0, stream>>>(b1, woutT, b_out, src, out,
                                                NTOK, 256, 256);
  // 5. y = LN(src2) -> yb (bf16; overwrites dead logits)
  ln_bf16<false><<<NTOK / 4, 256, 0, stream>>>(out, g2, beta2, yb, nullptr,
                                               nullptr);
  // 6. hid = relu(y @ w_fc1 + b_fc1) -> b1..b4 (89.1MB, all dead)
  gemm_mfma<2><<<dim3(MT, 8), 256, 0, stream>>>(yb, wfc1T, b_fc1, nullptr, hid,
                                                NTOK, 1024, 256);
  // 7. out = hid @ w_fc2 + b_fc2 + src2(d_out) -> d_out (read-then-write)
  gemm_mfma<3><<<dim3(MT, 2), 256, 0, stream>>>(hid, wfc2T, b_fc2, out, out,
                                                NTOK, 256, 1024);
}

// Round 6
// 412.399 us; speedup vs baseline: 1.2974x; 1.0064x over previous
//
#include <hip/hip_runtime.h>

// MSDeformAttn encoder layer — bf16 MFMA GEMMs (global_load_lds staging,
// XCD-chunked block swizzle, fused dispatches, fused LN2 epilogue) +
// wave-per-query deformable sampling on a HEAD-MAJOR value tensor
// (x-tap pairs contiguous -> dwordx4 gathers, half the VMEM instructions).
#define DMODEL 256
#define NHEAD 8
#define NPOINT 4
#define NLEVEL 4
#define DHEAD 32
#define MLPD 1024
#define BSZ 2
#define LQTOK 21760
#define NTOK (BSZ * LQTOK)  // 43520
#define LNEPS 1e-6f

typedef __attribute__((ext_vector_type(8))) short short8;
typedef __attribute__((ext_vector_type(4))) float f32x4;
typedef __attribute__((ext_vector_type(2))) float f32x2;

__device__ __forceinline__ float bf2f(unsigned short u) {
  unsigned int i = ((unsigned int)u) << 16;
  return __builtin_bit_cast(float, i);
}
__device__ __forceinline__ unsigned short f2bf(float f) {
  unsigned int i = __builtin_bit_cast(unsigned int, f);
  i += 0x7fff + ((i >> 16) & 1);  // round-to-nearest-even
  return (unsigned short)(i >> 16);
}
__device__ __forceinline__ float bflo(unsigned int u) {
  return __builtin_bit_cast(float, u << 16);
}
__device__ __forceinline__ float bfhi(unsigned int u) {
  return __builtin_bit_cast(float, u & 0xffff0000u);
}

// d += a * b.lo / b.hi  (VOP3P packed f32 FMA; scalar broadcast via op_sel)
__device__ __forceinline__ void pk_fma_blo(f32x2& d, f32x2 a, f32x2 b) {
  asm("v_pk_fma_f32 %0, %1, %2, %0 op_sel:[0,0,0] op_sel_hi:[1,0,1]"
      : "+v"(d)
      : "v"(a), "v"(b));
}
__device__ __forceinline__ void pk_fma_bhi(f32x2& d, f32x2 a, f32x2 b) {
  asm("v_pk_fma_f32 %0, %1, %2, %0 op_sel:[0,1,0] op_sel_hi:[1,1,1]"
      : "+v"(d)
      : "v"(a), "v"(b));
}

// async global->LDS, 16B per lane; lds dest = wave-uniform base + lane*16
__device__ __forceinline__ void gload_lds16(const unsigned short* g,
                                            unsigned short* lds) {
  __builtin_amdgcn_global_load_lds(
      (const __attribute__((address_space(1))) unsigned int*)g,
      (__attribute__((address_space(3))) unsigned int*)lds, 16, 0, 0);
}

// bijective XCD-chunked block swizzle (m204): consecutive wgid stay on one
// XCD and iterate the column index fastest -> A-panel L2 reuse.
__device__ __forceinline__ unsigned xcd_swz(unsigned orig, unsigned nwg) {
  unsigned xcd = orig & 7u, rest = orig >> 3;
  unsigned qq = nwg >> 3, rr = nwg & 7u;
  return (xcd < rr ? xcd * (qq + 1) : rr * (qq + 1) + (xcd - rr) * qq) + rest;
}

// ---------------- layernorm: wave-per-row, no LDS/barriers -----------------
// o = bf16(LN(in)*g + beta); also q = bf16(bf2f(o) + pos)
__global__ __launch_bounds__(256) void ln_bf16(
    const float* __restrict__ in, const float* __restrict__ g,
    const float* __restrict__ beta, unsigned short* __restrict__ o,
    const float* __restrict__ pos, unsigned short* __restrict__ q) {
  const int w = threadIdx.x >> 6, lane = threadIdx.x & 63;
  const size_t t = (size_t)blockIdx.x * 4 + w;
  const size_t base = t * DMODEL + lane * 4;
  float4 v = *(const float4*)(in + base);
  float s = (v.x + v.y) + (v.z + v.w);
#pragma unroll
  for (int off = 32; off; off >>= 1) s += __shfl_xor(s, off, 64);
  float mu = s * (1.0f / DMODEL);
  float dx = v.x - mu, dy = v.y - mu, dz = v.z - mu, dw = v.w - mu;
  float s2 = (dx * dx + dy * dy) + (dz * dz + dw * dw);
#pragma unroll
  for (int off = 32; off; off >>= 1) s2 += __shfl_xor(s2, off, 64);
  float rs = rsqrtf(s2 * (1.0f / DMODEL) + LNEPS);
  float4 gg = *(const float4*)(g + lane * 4);
  float4 bb = *(const float4*)(beta + lane * 4);
  unsigned short r0 = f2bf(dx * rs * gg.x + bb.x);
  unsigned short r1 = f2bf(dy * rs * gg.y + bb.y);
  unsigned short r2 = f2bf(dz * rs * gg.z + bb.z);
  unsigned short r3 = f2bf(dw * rs * gg.w + bb.w);
  unsigned int lo = ((unsigned int)r1 << 16) | r0;
  unsigned int hi = ((unsigned int)r3 << 16) | r2;
  *(uint2*)(o + base) = make_uint2(lo, hi);
  float4 p = *(const float4*)(pos + base);
  unsigned short q0 = f2bf(bf2f(r0) + p.x);
  unsigned short q1 = f2bf(bf2f(r1) + p.y);
  unsigned short q2 = f2bf(bf2f(r2) + p.z);
  unsigned short q3 = f2bf(bf2f(r3) + p.w);
  unsigned int ql = ((unsigned int)q1 << 16) | q0;
  unsigned int qh = ((unsigned int)q3 << 16) | q2;
  *(uint2*)(q + base) = make_uint2(ql, qh);
}

// ------ all weight transposes in ONE dispatch: Wt[n][k] = bf16(W[k][n]) ----
__global__ __launch_bounds__(256) void transpose_all(
    const float* __restrict__ w_val, const float* __restrict__ w_off,
    const float* __restrict__ w_attn, const float* __restrict__ w_out,
    const float* __restrict__ w_fc1, const float* __restrict__ w_fc2,
    unsigned short* __restrict__ wvalT, unsigned short* __restrict__ woffaT,
    unsigned short* __restrict__ woutT, unsigned short* __restrict__ wfc1T,
    unsigned short* __restrict__ wfc2T) {
  __shared__ float tile[32][33];
  int bid = blockIdx.x;
  const float* W;
  unsigned short* Wt;
  int K, N, rel;
  if (bid < 64) {
    W = w_val; Wt = wvalT; K = 256; N = 256; rel = bid;
  } else if (bid < 128) {
    W = w_off; Wt = woffaT; K = 256; N = 256; rel = bid - 64;
  } else if (bid < 160) {
    W = w_attn; Wt = woffaT + 256 * 256; K = 256; N = 128; rel = bid - 128;
  } else if (bid < 224) {
    W = w_out; Wt = woutT; K = 256; N = 256; rel = bid - 160;
  } else if (bid < 480) {
    W = w_fc1; Wt = wfc1T; K = 256; N = 1024; rel = bid - 224;
  } else {
    W = w_fc2; Wt = wfc2T; K = 1024; N = 256; rel = bid - 480;
  }
  int ktiles = K >> 5;
  int k0 = (rel % ktiles) * 32, n0 = (rel / ktiles) * 32;
  int tx = threadIdx.x & 31, ty = threadIdx.x >> 5;  // 32 x 8
  for (int i = ty; i < 32; i += 8)
    tile[i][tx] = W[(size_t)(k0 + i) * N + n0 + tx];
  __syncthreads();
  for (int i = ty; i < 32; i += 8)
    Wt[(size_t)(n0 + i) * K + k0 + tx] = f2bf(tile[tx][i]);
}

// ---------------- bf16 MFMA GEMM core (m97 structure) ----------------------
// Tile 128x128, BK=32. OMODE: 2=bf16+relu, 3=f32+res.
template <int OMODE>
__global__ __launch_bounds__(256) void gemm_mfma(
    const unsigned short* __restrict__ A, const unsigned short* __restrict__ Wt,
    const float* __restrict__ bias, const float* __restrict__ res,
    void* __restrict__ Cout, int M, int N, int K) {
  __shared__ __attribute__((aligned(16))) unsigned short As[128 * 32];
  __shared__ __attribute__((aligned(16))) unsigned short Bs[128 * 32];
  const int tid = threadIdx.x;
  const unsigned gy = gridDim.y;
  const unsigned wgid = xcd_swz(blockIdx.y * gridDim.x + blockIdx.x,
                                gridDim.x * gy);
  const int m0 = (int)(wgid / gy) * 128;
  const int n0 = (int)(wgid % gy) * 128;
  const int wave = tid >> 6, lane = tid & 63;
  const int wm = (wave & 1) * 64, wn = (wave >> 1) * 64;
  const int lr = lane & 15, quad = lane >> 4;
  f32x4 acc[4][4] = {};
  for (int k0 = 0; k0 < K; k0 += 32) {
    __syncthreads();
#pragma unroll
    for (int r = 0; r < 2; r++) {
      int c = r * 256 + tid;
      int row = c >> 2, col8 = (c & 3) * 8;
      gload_lds16(Wt + (size_t)(n0 + row) * K + k0 + col8,
                  &Bs[(r * 256 + wave * 64) * 8]);
    }
#pragma unroll
    for (int r = 0; r < 2; r++) {
      int c = r * 256 + tid;
      int row = c >> 2, col8 = (c & 3) * 8;
      gload_lds16(A + (size_t)(m0 + row) * K + k0 + col8,
                  &As[(r * 256 + wave * 64) * 8]);
    }
    __syncthreads();
    short8 af[4], bfr[4];
#pragma unroll
    for (int i = 0; i < 4; i++)
      af[i] = *(const short8*)(&As[(wm + i * 16 + lr) * 32 + quad * 8]);
#pragma unroll
    for (int j = 0; j < 4; j++)
      bfr[j] = *(const short8*)(&Bs[(wn + j * 16 + lr) * 32 + quad * 8]);
#pragma unroll
    for (int i = 0; i < 4; i++)
#pragma unroll
      for (int j = 0; j < 4; j++)
        acc[i][j] = __builtin_amdgcn_mfma_f32_16x16x32_bf16(af[i], bfr[j],
                                                            acc[i][j], 0, 0, 0);
  }
#pragma unroll
  for (int i = 0; i < 4; i++) {
    int rbase = m0 + wm + i * 16 + quad * 4;
#pragma unroll
    for (int j = 0; j < 4; j++) {
      int col = n0 + wn + j * 16 + lr;
      float bv = bias[col];
#pragma unroll
      for (int r = 0; r < 4; r++) {
        size_t idx = (size_t)(rbase + r) * N + col;
        float v = acc[i][j][r] + bv;
        if (OMODE == 2) v = fmaxf(v, 0.0f);
        if (OMODE == 3) {
          ((float*)Cout)[idx] = v + res[idx];
        } else {
          ((unsigned short*)Cout)[idx] = f2bf(v);
        }
      }
    }
  }
}

// ---- fused val + off|attn GEMM: one dispatch, grid (340, 5) ----
// ny<2 -> val = x @ w_val (HEAD-MAJOR output [(b*8+h)][lq][32]);
// ny>=2 -> [off|logits] = q @ [w_off|w_attn].
__global__ __launch_bounds__(256) void gemm_vo(
    const unsigned short* __restrict__ Ax, const unsigned short* __restrict__ Aq,
    const unsigned short* __restrict__ Wval,
    const unsigned short* __restrict__ Woa, const float* __restrict__ bval,
    const float* __restrict__ boff, const float* __restrict__ battn,
    unsigned short* __restrict__ oval, unsigned short* __restrict__ ooff,
    unsigned short* __restrict__ olg) {
  __shared__ __attribute__((aligned(16))) unsigned short As[128 * 32];
  __shared__ __attribute__((aligned(16))) unsigned short Bs[128 * 32];
  const int tid = threadIdx.x;
  const unsigned gy = gridDim.y;  // 5
  const unsigned wgid = xcd_swz(blockIdx.y * gridDim.x + blockIdx.x,
                                gridDim.x * gy);
  const int m0 = (int)(wgid / gy) * 128;
  const int ny = (int)(wgid % gy);
  const bool isval = ny < 2;
  const unsigned short* A = isval ? Ax : Aq;
  const unsigned short* Wt = isval ? Wval : Woa;
  const int n0 = isval ? ny * 128 : (ny - 2) * 128;
  const int wave = tid >> 6, lane = tid & 63;
  const int wm = (wave & 1) * 64, wn = (wave >> 1) * 64;
  const int lr = lane & 15, quad = lane >> 4;
  f32x4 acc[4][4] = {};
  for (int k0 = 0; k0 < 256; k0 += 32) {
    __syncthreads();
#pragma unroll
    for (int r = 0; r < 2; r++) {
      int c = r * 256 + tid;
      int row = c >> 2, col8 = (c & 3) * 8;
      gload_lds16(Wt + (size_t)(n0 + row) * 256 + k0 + col8,
                  &Bs[(r * 256 + wave * 64) * 8]);
    }
#pragma unroll
    for (int r = 0; r < 2; r++) {
      int c = r * 256 + tid;
      int row = c >> 2, col8 = (c & 3) * 8;
      gload_lds16(A + (size_t)(m0 + row) * 256 + k0 + col8,
                  &As[(r * 256 + wave * 64) * 8]);
    }
    __syncthreads();
    short8 af[4], bfr[4];
#pragma unroll
    for (int i = 0; i < 4; i++)
      af[i] = *(const short8*)(&As[(wm + i * 16 + lr) * 32 + quad * 8]);
#pragma unroll
    for (int j = 0; j < 4; j++)
      bfr[j] = *(const short8*)(&Bs[(wn + j * 16 + lr) * 32 + quad * 8]);
#pragma unroll
    for (int i = 0; i < 4; i++)
#pragma unroll
      for (int j = 0; j < 4; j++)
        acc[i][j] = __builtin_amdgcn_mfma_f32_16x16x32_bf16(af[i], bfr[j],
                                                            acc[i][j], 0, 0, 0);
  }
#pragma unroll
  for (int i = 0; i < 4; i++) {
    int rbase = m0 + wm + i * 16 + quad * 4;
#pragma unroll
    for (int j = 0; j < 4; j++) {
      int col = n0 + wn + j * 16 + lr;
      float bv = isval ? bval[col]
                       : (col < 256 ? boff[col] : battn[col - 256]);
#pragma unroll
      for (int r = 0; r < 4; r++) {
        int row = rbase + r;
        float v = acc[i][j][r] + bv;
        if (isval) {
          int b_ = row >= LQTOK ? 1 : 0;
          int lq = row - b_ * LQTOK;
          int h = col >> 5, cc = col & 31;
          oval[(((size_t)b_ * 8 + h) * LQTOK + lq) * 32 + cc] = f2bf(v);
        } else if (col < 256) {
          ooff[(size_t)row * 256 + col] = f2bf(v);
        } else {
          olg[(size_t)row * 128 + (col - 256)] = f2bf(v);
        }
      }
    }
  }
}

// ---- out-projection GEMM with FUSED residual + LayerNorm epilogue ----
// Tile 64x256 (full row per block), grid NTOK/64. Writes src2 (f32, for the
// fc2 residual) and y = LN(src2)*g2+beta2 (bf16) in one pass.
// var = E[x^2]-mu^2 (f32, values O(1) -> no cancellation issue).
__global__ __launch_bounds__(256) void gemm_out_ln(
    const unsigned short* __restrict__ A, const unsigned short* __restrict__ Wt,
    const float* __restrict__ bias, const float* __restrict__ src,
    const float* __restrict__ g2, const float* __restrict__ beta2,
    float* __restrict__ src2, unsigned short* __restrict__ y) {
  __shared__ __attribute__((aligned(16))) unsigned short As[64 * 32];
  __shared__ __attribute__((aligned(16))) unsigned short Bs[256 * 32];
  __shared__ float red[2][64][2];
  const int tid = threadIdx.x;
  const int m0 = (int)blockIdx.x * 64;
  const int wave = tid >> 6, lane = tid & 63;
  const int wm = (wave >> 1) * 32, wn = (wave & 1) * 128;
  const int lr = lane & 15, quad = lane >> 4;
  f32x4 acc[2][8] = {};
  for (int k0 = 0; k0 < 256; k0 += 32) {
    __syncthreads();
    {
      int row = tid >> 2, col8 = (tid & 3) * 8;
      gload_lds16(A + (size_t)(m0 + row) * 256 + k0 + col8,
                  &As[(wave * 64) * 8]);
    }
#pragma unroll
    for (int r = 0; r < 4; r++) {
      int c = r * 256 + tid;
      int row = c >> 2, col8 = (c & 3) * 8;
      gload_lds16(Wt + (size_t)row * 256 + k0 + col8,
                  &Bs[(r * 256 + wave * 64) * 8]);
    }
    __syncthreads();
    short8 af[2], bfr[8];
#pragma unroll
    for (int i = 0; i < 2; i++)
      af[i] = *(const short8*)(&As[(wm + i * 16 + lr) * 32 + quad * 8]);
#pragma unroll
    for (int j = 0; j < 8; j++)
      bfr[j] = *(const short8*)(&Bs[(wn + j * 16 + lr) * 32 + quad * 8]);
#pragma unroll
    for (int i = 0; i < 2; i++)
#pragma unroll
      for (int j = 0; j < 8; j++)
        acc[i][j] = __builtin_amdgcn_mfma_f32_16x16x32_bf16(af[i], bfr[j],
                                                            acc[i][j], 0, 0, 0);
  }
  // epilogue pass 1: src2 = acc + bias + src; accumulate row sums
  float s1[2][4] = {}, s2[2][4] = {};
#pragma unroll
  for (int i = 0; i < 2; i++)
#pragma unroll
    for (int j = 0; j < 8; j++) {
      int col = wn + j * 16 + lr;
      float bv = bias[col];
#pragma unroll
      for (int r = 0; r < 4; r++) {
        int row = m0 + wm + i * 16 + quad * 4 + r;
        size_t idx = (size_t)row * 256 + col;
        float v = acc[i][j][r] + bv + src[idx];
        src2[idx] = v;
        acc[i][j][r] = v;
        s1[i][r] += v;
        s2[i][r] = fmaf(v, v, s2[i][r]);
      }
    }
  // reduce over the 16 lr-lanes (stays within quad group)
#pragma unroll
  for (int i = 0; i < 2; i++)
#pragma unroll
    for (int r = 0; r < 4; r++)
#pragma unroll
      for (int s = 1; s < 16; s <<= 1) {
        s1[i][r] += __shfl_xor(s1[i][r], s, 64);
        s2[i][r] += __shfl_xor(s2[i][r], s, 64);
      }
  if (lr == 0) {
#pragma unroll
    for (int i = 0; i < 2; i++)
#pragma unroll
      for (int r = 0; r < 4; r++) {
        int rl = wm + i * 16 + quad * 4 + r;
        red[0][rl][wave & 1] = s1[i][r];
        red[1][rl][wave & 1] = s2[i][r];
      }
  }
  __syncthreads();
  // epilogue pass 2: y = (v - mu)*rs*g2 + beta2
#pragma unroll
  for (int i = 0; i < 2; i++)
#pragma unroll
    for (int r = 0; r < 4; r++) {
      int rl = wm + i * 16 + quad * 4 + r;
      float S1 = red[0][rl][0] + red[0][rl][1];
      float S2 = red[1][rl][0] + red[1][rl][1];
      float mu = S1 * (1.0f / DMODEL);
      float var = S2 * (1.0f / DMODEL) - mu * mu;
      float rs = rsqrtf(var + LNEPS);
      int row = m0 + rl;
#pragma unroll
      for (int j = 0; j < 8; j++) {
        int col = wn + j * 16 + lr;
        float yv = (acc[i][j][r] - mu) * rs * g2[col] + beta2[col];
        y[(size_t)row * 256 + col] = f2bf(yv);
      }
    }
}

// ---------------- deformable sampling + fused softmax ----------------
// Wave-per-query, 8 queries/block, NO __syncthreads. val is HEAD-MAJOR
// [(b*8+h)][token][32ch] so the (x, x+1) bilinear tap pair is 128B
// contiguous. Phase 1 folds edge clamping into per-token weights A/B
// (token xb and xb+1, xb = clamp(x0,0,HW-2)); stores 2 row bases + 4
// token weights per (pt,h). Phase 2: lane=(h2,g): dwordx4 gather covers
// BOTH x-taps (g<4 -> token xb, g>=4 -> xb+1); per-channel sums finished
// by one shfl_xor(4) combine; 32 VMEM instr/query (was 64).
__global__ __launch_bounds__(512) void deform_sample(
    const unsigned short* __restrict__ val, const unsigned short* __restrict__ off,
    const unsigned short* __restrict__ logits, const float* __restrict__ refp,
    unsigned short* __restrict__ out) {
  __shared__ __attribute__((aligned(16))) int2 sIdx[8][16][8];
  __shared__ __attribute__((aligned(16))) float sW[8][16][8][4];
  const int w = threadIdx.x >> 6, lane = threadIdx.x & 63;
  const int bq = blockIdx.x * 8 + w;
  const int b = __builtin_amdgcn_readfirstlane(bq / LQTOK);
  {
    const int HW_[4] = {128, 64, 32, 16};
    const int LSI_[4] = {0, 16384, 20480, 21504};
    int u0 = 2 * lane;
    int h = u0 >> 4;
    int lvl = (u0 >> 2) & 3;
    int pt0 = u0 & 15;
    int HW = HW_[lvl];
    float2 rp = ((const float2*)refp)[(size_t)bq * 4 + lvl];
    uint2 ov = *(const uint2*)(off + (size_t)bq * 256 + 4 * lane);
    unsigned int lgu = *(const unsigned int*)(logits + (size_t)bq * 128 + 2 * lane);
    float lg0 = bflo(lgu), lg1 = bfhi(lgu);
    // fused softmax over this head's 16 logits (8 lanes x 2)
    float mx = fmaxf(lg0, lg1);
#pragma unroll
    for (int s = 1; s < 8; s <<= 1) mx = fmaxf(mx, __shfl_xor(mx, s, 64));
    float e0 = expf(lg0 - mx), e1 = expf(lg1 - mx);
    float es = e0 + e1;
#pragma unroll
    for (int s = 1; s < 8; s <<= 1) es += __shfl_xor(es, s, 64);
    float inv = 1.0f / es;
    float a01[2] = {e0 * inv, e1 * inv};
    unsigned int ovv[2] = {ov.x, ov.y};
#pragma unroll
    for (int c = 0; c < 2; c++) {
      float x = fmaf(rp.x, (float)HW, bflo(ovv[c])) - 0.5f;
      float y = fmaf(rp.y, (float)HW, bfhi(ovv[c])) - 0.5f;
      float xf = floorf(x), yf = floorf(y);
      int x0 = (int)xf, y0 = (int)yf;
      float lx = x - xf, ly = y - yf;
      int x0c = min(max(x0, 0), HW - 1);
      int x1c = min(max(x0 + 1, 0), HW - 1);
      int y0c = min(max(y0, 0), HW - 1);
      int y1c = min(max(y0 + 1, 0), HW - 1);
      float m0x = (x0 >= 0 && x0 < HW) ? 1.f : 0.f;
      float m1x = (x0 + 1 >= 0 && x0 + 1 < HW) ? 1.f : 0.f;
      float m0y = (y0 >= 0 && y0 < HW) ? 1.f : 0.f;
      float m1y = (y0 + 1 >= 0 && y0 + 1 < HW) ? 1.f : 0.f;
      float a = a01[c];
      float w00 = (1.f - lx) * (1.f - ly) * m0x * m0y * a;
      float w01 = lx * (1.f - ly) * m1x * m0y * a;
      float w10 = (1.f - lx) * ly * m0x * m1y * a;
      float w11 = lx * ly * m1x * m1y * a;
      int xb = min(max(x0, 0), HW - 2);
      bool c0 = (x0c == xb), c1 = (x1c == xb);
      float A0 = (c0 ? w00 : 0.f) + (c1 ? w01 : 0.f);
      float B0 = (c0 ? 0.f : w00) + (c1 ? 0.f : w01);
      float A1 = (c0 ? w10 : 0.f) + (c1 ? w11 : 0.f);
      float B1 = (c0 ? 0.f : w10) + (c1 ? 0.f : w11);
      int pt = pt0 + c;
      int hs = h ^ (pt & 7);
      sIdx[w][pt][hs] = make_int2((LSI_[lvl] + y0c * HW + xb) * 64,
                                  (LSI_[lvl] + y1c * HW + xb) * 64);
      *(float4*)sW[w][pt][hs] = make_float4(A0, B0, A1, B1);
    }
  }
  // wave-synchronous handoff: same wave wrote, same wave reads.
  __builtin_amdgcn_wave_barrier();
  const int h2 = lane >> 3, g = lane & 7;
  const char* base2 = (const char*)val +
                      ((size_t)(b * 8 + h2) * LQTOK) * 64 + g * 16;
  f32x2 a4[4] = {};
#pragma unroll
  for (int pb = 0; pb < 4; pb++) {
    int2 tt[4];
    f32x4 wt4[4];
#pragma unroll
    for (int p = 0; p < 4; p++) {
      int pt = pb * 4 + p;
      int hs = h2 ^ (pt & 7);
      tt[p] = sIdx[w][pt][hs];
      wt4[p] = *(const f32x4*)sW[w][pt][hs];
    }
    uint4 v0[4], v1[4];
#pragma unroll
    for (int p = 0; p < 4; p++) {
      v0[p] = *(const uint4*)(base2 + (unsigned)tt[p].x);
      v1[p] = *(const uint4*)(base2 + (unsigned)tt[p].y);
    }
#pragma unroll
    for (int p = 0; p < 4; p++) {
      f32x2 wp;
      wp[0] = (g < 4) ? wt4[p][0] : wt4[p][1];  // row y0 weight for my token
      wp[1] = (g < 4) ? wt4[p][2] : wt4[p][3];  // row y1 weight
      f32x2 u;
      u[0] = bflo(v0[p].x); u[1] = bfhi(v0[p].x); pk_fma_blo(a4[0], u, wp);
      u[0] = bflo(v0[p].y); u[1] = bfhi(v0[p].y); pk_fma_blo(a4[1], u, wp);
      u[0] = bflo(v0[p].z); u[1] = bfhi(v0[p].z); pk_fma_blo(a4[2], u, wp);
      u[0] = bflo(v0[p].w); u[1] = bfhi(v0[p].w); pk_fma_blo(a4[3], u, wp);
      u[0] = bflo(v1[p].x); u[1] = bfhi(v1[p].x); pk_fma_bhi(a4[0], u, wp);
      u[0] = bflo(v1[p].y); u[1] = bfhi(v1[p].y); pk_fma_bhi(a4[1], u, wp);
      u[0] = bflo(v1[p].z); u[1] = bfhi(v1[p].z); pk_fma_bhi(a4[2], u, wp);
      u[0] = bflo(v1[p].w); u[1] = bfhi(v1[p].w); pk_fma_bhi(a4[3], u, wp);
    }
  }
  // combine the two x-token halves (lanes g and g^4 hold the same channels)
#pragma unroll
  for (int qv = 0; qv < 4; qv++) {
    a4[qv][0] += __shfl_xor(a4[qv][0], 4, 64);
    a4[qv][1] += __shfl_xor(a4[qv][1], 4, 64);
  }
  if (g < 4) {
    uint4 o;
    o.x = ((unsigned)f2bf(a4[0][1]) << 16) | f2bf(a4[0][0]);
    o.y = ((unsigned)f2bf(a4[1][1]) << 16) | f2bf(a4[1][0]);
    o.z = ((unsigned)f2bf(a4[2][1]) << 16) | f2bf(a4[2][0]);
    o.w = ((unsigned)f2bf(a4[3][1]) << 16) | f2bf(a4[3][0]);
    *(uint4*)(out + (size_t)bq * 256 + h2 * 32 + g * 8) = o;
  }
}

// ---------------- launch ----------------
extern "C" void kernel_launch(void* const* d_in, const int* in_sizes, int n_in,
                              void* d_out, int out_size, void* d_ws,
                              size_t ws_size, hipStream_t stream) {
  const float* src    = (const float*)d_in[0];
  const float* pos    = (const float*)d_in[1];
  const float* refp   = (const float*)d_in[2];
  const float* g1     = (const float*)d_in[5];
  const float* beta1  = (const float*)d_in[6];
  const float* w_off  = (const float*)d_in[7];
  const float* b_off  = (const float*)d_in[8];
  const float* w_attn = (const float*)d_in[9];
  const float* b_attn = (const float*)d_in[10];
  const float* w_val  = (const float*)d_in[11];
  const float* b_val  = (const float*)d_in[12];
  const float* w_out  = (const float*)d_in[13];
  const float* b_out  = (const float*)d_in[14];
  const float* g2     = (const float*)d_in[15];
  const float* beta2  = (const float*)d_in[16];
  const float* w_fc1  = (const float*)d_in[17];
  const float* b_fc1  = (const float*)d_in[18];
  const float* w_fc2  = (const float*)d_in[19];
  const float* b_fc2  = (const float*)d_in[20];
  float* out = (float*)d_out;

  // Workspace layout (byte budget identical to the verified baseline):
  //  b1..b4 (4 x 22.28MB, contiguous) double as the full FFN hidden (89.1MB)
  //  b5 (44.6MB) holds logits bf16 then y bf16; src2 lives in d_out.
  const size_t NT = (size_t)NTOK;
  unsigned short* b1 = (unsigned short*)d_ws;  // x bf16 -> sampled -> hid
  unsigned short* b2 = b1 + NT * 256;          // val bf16 (head-major) -> hid
  unsigned short* b3 = b2 + NT * 256;          // off bf16          -> hid
  unsigned short* b4 = b3 + NT * 256;          // q bf16            -> hid
  unsigned short* b5 = b4 + NT * 256;          // logits bf16 -> y bf16
  unsigned short* wvalT  = b5 + NT * 512;      // [256][256]
  unsigned short* woffaT = wvalT + 256 * 256;  // [384][256] (off|attn merged)
  unsigned short* woutT  = woffaT + 384 * 256; // [256][256]
  unsigned short* wfc1T  = woutT + 256 * 256;  // [1024][256]
  unsigned short* wfc2T  = wfc1T + 1024 * 256; // [256][1024]

  unsigned short* qb  = b4;  // q = x+pos, bf16 [NT][256]
  unsigned short* lgb = b5;  // logits bf16 [NT][128]
  unsigned short* yb  = b5;  // y bf16 [NT][256] (after logits dead)
  unsigned short* hid = b1;  // FFN hidden bf16 [NT][1024] spans b1..b4

  const int MT = NTOK / 128;  // 340

  // 0. all weight transposes (f32 -> bf16, [K][N] -> [N][K]) in ONE dispatch
  transpose_all<<<736, 256, 0, stream>>>(w_val, w_off, w_attn, w_out, w_fc1,
                                         w_fc2, wvalT, woffaT, woutT, wfc1T,
                                         wfc2T);
  // 1. x = LN(src) -> b1 (bf16); q = bf16(x)+pos -> qb (bf16)
  ln_bf16<<<NTOK / 4, 256, 0, stream>>>(src, g1, beta1, b1, pos, qb);
  // 2. fused: val(head-major) = x @ w_val -> b2 ; [off|logits] = q @ woffa
  gemm_vo<<<dim3(MT, 5), 256, 0, stream>>>(b1, qb, wvalT, woffaT, b_val, b_off,
                                           b_attn, b2, b3, lgb);
  // 3. sampling (fused softmax) -> b1 (x dead, q dead)
  deform_sample<<<NTOK / 8, 512, 0, stream>>>(b2, b3, lgb, refp, b1);
  // 4. src2 = sampled @ w_out + b_out + src -> d_out (f32) AND
  //    y = LN(src2) -> yb (bf16), fused in one dispatch
  gemm_out_ln<<<NTOK / 64, 256, 0, stream>>>(b1, woutT, b_out, src, g2, beta2,
                                             out, yb);
  // 5. hid = relu(y @ w_fc1 + b_fc1) -> b1..b4 (89.1MB, all dead)
  gemm_mfma<2><<<dim3(MT, 8), 256, 0, stream>>>(yb, wfc1T, b_fc1, nullptr, hid,
                                                NTOK, 1024, 256);
  // 6. out = hid @ w_fc2 + b_fc2 + src2(d_out) -> d_out (read-then-write)
  gemm_mfma<3><<<dim3(MT, 2), 256, 0, stream>>>(hid, wfc2T, b_fc2, out, out,
                                                NTOK, 256, 1024);
}